// Round 6
// baseline (350.824 us; speedup 1.0000x reference)
//
#include <hip/hip_runtime.h>
#include <math.h>

// Problem dims (fixed): B=128, S=64, H=128, STATIC=DYNAMIC=2
// Outputs: tour_idx [B,S] (as f32), tour_logp [B,S] -> d_out 16384 f32

#define K1  1.44269504088896340736f   // log2(e)
#define K2  2.88539008177792681472f   // 2*log2(e)
#define LN2 0.69314718055994530942f

// ---------------- ws layout (float offsets) ----------------
#define WS_M     0                       // [384][2]   M = wih @ decoder_w
#define WS_C     768                     // [384]      c = wih @ decoder_b + bih
#define WS_PREA  1152                    // [B][128][64] EA = exp2(K2*(W1@sh + W2@dh))
#define WS_PREP  (WS_PREA + 128*8192)    // [B][128][64] EP = exp2(K2*(P1@sh))
#define WS_Q     (WS_PREP + 128*8192)    // [B][128][64] Q  = P2@sh

// LDS swizzles (conflict-free for the specific read patterns)
#define SW(h)   ((h) + ((h) >> 2))            // 128-vec read at stride 8
#define PADH(h) ((((h) >> 4) * 20) + ((h) & 15))  // 128-vec float4 read, 16-chunks

// ---- DPP cross-lane (VALU-speed; rows=16 lanes) ----
template <int CTRL>
__device__ __forceinline__ float dppf(float x) {
  int xi = __builtin_bit_cast(int, x);
  return __builtin_bit_cast(float,
      __builtin_amdgcn_update_dpp(xi, xi, CTRL, 0xF, 0xF, false));
}
template <int CTRL>
__device__ __forceinline__ int dppi(int x) {
  return __builtin_amdgcn_update_dpp(x, x, CTRL, 0xF, 0xF, false);
}
// 0xB1=quad xor1, 0x4E=quad xor2, 0x141=row_half_mirror, 0x128=row_ror:8
__device__ __forceinline__ float sum8(float x) {   // 8 consecutive lanes
  x += dppf<0xB1>(x); x += dppf<0x4E>(x); x += dppf<0x141>(x); return x;
}
__device__ __forceinline__ float sum16(float x) {  // 16 consecutive lanes
  x += dppf<0xB1>(x); x += dppf<0x4E>(x); x += dppf<0x141>(x); x += dppf<0x128>(x);
  return x;
}
__device__ __forceinline__ float sum64(float x) {
  x = sum16(x); x += __shfl_xor(x, 16); x += __shfl_xor(x, 32); return x;
}
__device__ __forceinline__ float max64(float x) {
  x = fmaxf(x, dppf<0xB1>(x)); x = fmaxf(x, dppf<0x4E>(x));
  x = fmaxf(x, dppf<0x141>(x)); x = fmaxf(x, dppf<0x128>(x));
  x = fmaxf(x, __shfl_xor(x, 16)); x = fmaxf(x, __shfl_xor(x, 32)); return x;
}
#define RCP(x)  __builtin_amdgcn_rcpf(x)
#define EXP2(x) __builtin_amdgcn_exp2f(x)

// ---------------- tiny precompute: GRU input-path folding ----------------
__global__ __launch_bounds__(256) void prep_small(
    const float* __restrict__ wih, const float* __restrict__ decw,
    const float* __restrict__ decb, const float* __restrict__ bih,
    float* __restrict__ ws) {
  int gid = blockIdx.x * 256 + threadIdx.x;
  if (gid < 384) {
    float m0 = 0.f, m1 = 0.f, cc = 0.f;
    for (int k = 0; k < 128; ++k) {
      float w = wih[gid * 128 + k];
      m0 += w * decw[k * 2 + 0];
      m1 += w * decw[k * 2 + 1];
      cc += w * decb[k];
    }
    ws[WS_M + gid * 2 + 0] = m0;
    ws[WS_M + gid * 2 + 1] = m1;
    ws[WS_C + gid] = cc + bih[gid];
  }
}

// ---------------- big precompute: EA / EP / Q per batch ------------------
__global__ __launch_bounds__(256) void prep_big(
    const float* __restrict__ statics, const float* __restrict__ dynamics,
    const float* __restrict__ sw, const float* __restrict__ sb,
    const float* __restrict__ dw, const float* __restrict__ db,
    const float* __restrict__ attn_W, const float* __restrict__ ptr_W,
    float* __restrict__ ws) {
  __shared__ __align__(16) float sh[128 * 64];
  __shared__ __align__(16) float dh[128 * 64];
  __shared__ float st[128];
  __shared__ float dy[128];
  int b = blockIdx.x >> 3;
  int hq = blockIdx.x & 7;
  int t = threadIdx.x;
  if (t < 128) st[t] = statics[b * 128 + t];
  else         dy[t - 128] = dynamics[b * 128 + (t - 128)];
  __syncthreads();
  for (int e = t; e < 8192; e += 256) {
    int h = e >> 6, s = e & 63;
    sh[e] = sw[h * 2 + 0] * st[s] + sw[h * 2 + 1] * st[64 + s] + sb[h];
    dh[e] = dw[h * 2 + 0] * dy[s] + dw[h * 2 + 1] * dy[64 + s] + db[h];
  }
  __syncthreads();
  int hh = hq * 16 + (t >> 4);
  int s0 = (t & 15) * 4;
  float4 pA = {0, 0, 0, 0}, pP = {0, 0, 0, 0}, qq = {0, 0, 0, 0};
  for (int k = 0; k < 128; ++k) {
    float4 sv = *(const float4*)&sh[k * 64 + s0];
    float4 dv = *(const float4*)&dh[k * 64 + s0];
    float w1 = attn_W[hh * 384 + k];
    float w2 = attn_W[hh * 384 + 128 + k];
    float p1 = ptr_W[hh * 256 + k];
    float p2 = ptr_W[hh * 256 + 128 + k];
    pA.x += w1 * sv.x + w2 * dv.x;  pA.y += w1 * sv.y + w2 * dv.y;
    pA.z += w1 * sv.z + w2 * dv.z;  pA.w += w1 * sv.w + w2 * dv.w;
    pP.x += p1 * sv.x;  pP.y += p1 * sv.y;  pP.z += p1 * sv.z;  pP.w += p1 * sv.w;
    qq.x += p2 * sv.x;  qq.y += p2 * sv.y;  qq.z += p2 * sv.z;  qq.w += p2 * sv.w;
  }
  // store exp-transformed score bases (shared-exp tanh trick)
  float4 eA, eP;
  eA.x = exp2f(K2 * pA.x); eA.y = exp2f(K2 * pA.y);
  eA.z = exp2f(K2 * pA.z); eA.w = exp2f(K2 * pA.w);
  eP.x = exp2f(K2 * pP.x); eP.y = exp2f(K2 * pP.y);
  eP.z = exp2f(K2 * pP.z); eP.w = exp2f(K2 * pP.w);
  int o = b * 8192 + hh * 64 + s0;
  *(float4*)&ws[WS_PREA + o] = eA;
  *(float4*)&ws[WS_PREP + o] = eP;
  *(float4*)&ws[WS_Q + o]    = qq;
}

// ---------------- main recurrence: 1 block/batch, 1024 thr, 64 steps ----
// 16 waves = 4 waves/EU (exactly one block/CU).  amdgpu_waves_per_eu(4,4)
// pins the allocator's occupancy target -> VGPR cap 512/4 = 128, which the
// ~120 live floats/thread need.  (launch_bounds(1024,4) failed to do this:
// round-5 A/B showed VGPR=64 + 9.3 MB scratch writes, byte-identical to
// round 4.)  No libm; DPP reductions; tanh = 1-2*rcp(EA*F+1).
__global__
__attribute__((amdgpu_flat_work_group_size(1024, 1024)))
__attribute__((amdgpu_waves_per_eu(4, 4)))
void drl4tsp_main(
    const float* __restrict__ statics, const float* __restrict__ x0,
    const float* __restrict__ whh, const float* __restrict__ attn_W,
    const float* __restrict__ bhh_g, const float* __restrict__ attn_v,
    const float* __restrict__ ptr_v, const float* __restrict__ ws,
    float* __restrict__ out) {
  __shared__ __align__(16) float h_lds[160];   // PADH layout
  __shared__ float u3f[160];                   // SW layout: exp2(K2*u3[h])
  __shared__ float u2f[160];                   // SW layout: exp2(K2*u2[h])
  __shared__ float av2s[160];                  // SW: 2*attn_v
  __shared__ float pv2s[160];                  // SW: 2*ptr_v
  __shared__ float a_lds[64];
  __shared__ float l_lds[64];
  __shared__ float stt[128];

  const int b    = blockIdx.x;
  const int t    = threadIdx.x;
  const int lane = t & 63;
  const int g    = t >> 3;   // 0..127 row (matvec map)
  const int o    = t & 7;    // k/s octant
  const int s    = t >> 4;   // 0..63 column (score map)
  const int hg   = t & 15;   // h-group of 8

  // ---- register-resident weights (88 floats) ----
  float wr0[16], wr1[16], wr2[16], w3r[16];
  {
    const float4* pr = (const float4*)(whh + g * 128 + o * 16);
    const float4* pz = (const float4*)(whh + (128 + g) * 128 + o * 16);
    const float4* pn = (const float4*)(whh + (256 + g) * 128 + o * 16);
    const float4* p3 = (const float4*)(attn_W + g * 384 + 256 + o * 16);
#pragma unroll
    for (int i = 0; i < 4; ++i) {
      float4 a = pr[i], c = pz[i], d = pn[i], e = p3[i];
      wr0[4*i] = a.x; wr0[4*i+1] = a.y; wr0[4*i+2] = a.z; wr0[4*i+3] = a.w;
      wr1[4*i] = c.x; wr1[4*i+1] = c.y; wr1[4*i+2] = c.z; wr1[4*i+3] = c.w;
      wr2[4*i] = d.x; wr2[4*i+1] = d.y; wr2[4*i+2] = d.z; wr2[4*i+3] = d.w;
      w3r[4*i] = e.x; w3r[4*i+1] = e.y; w3r[4*i+2] = e.z; w3r[4*i+3] = e.w;
    }
  }
  float qr[8];
  {
    const float4* pq = (const float4*)(ws + WS_Q + b * 8192 + g * 64 + o * 8);
    float4 v0 = pq[0], v1 = pq[1];
    qr[0]=v0.x; qr[1]=v0.y; qr[2]=v0.z; qr[3]=v0.w;
    qr[4]=v1.x; qr[5]=v1.y; qr[6]=v1.z; qr[7]=v1.w;
  }
  float pa[8], pp[8], cav = 0.f, cpv = 0.f;
#pragma unroll
  for (int i = 0; i < 8; ++i) {
    int h = hg * 8 + i;
    pa[i] = ws[WS_PREA + b * 8192 + h * 64 + s];
    pp[i] = ws[WS_PREP + b * 8192 + h * 64 + s];
    cav += attn_v[h];
    cpv += ptr_v[h];
  }
  const float* Mm = ws + WS_M;
  const float* Cc = ws + WS_C;
  const float mR0 = Mm[g * 2],       mR1 = Mm[g * 2 + 1];
  const float cRt = Cc[g] + bhh_g[g];
  const float mZ0 = Mm[(128+g) * 2], mZ1 = Mm[(128+g) * 2 + 1];
  const float cZt = Cc[128 + g] + bhh_g[128 + g];
  const float mN0 = Mm[(256+g) * 2], mN1 = Mm[(256+g) * 2 + 1];
  const float cN0 = Cc[256 + g],     bN  = bhh_g[256 + g];

  if (t < 128) {
    stt[t] = statics[b * 128 + t];
    av2s[SW(t)] = 2.0f * attn_v[t];
    pv2s[SW(t)] = 2.0f * ptr_v[t];
  }
  __syncthreads();

  float hreg = 0.f, ghr = 0.f, ghz = 0.f, ghn = 0.f;
  float d0 = x0[0], d1 = x0[1];

  for (int step = 0; step < 64; ++step) {
    // ---- P1: GRU gates (pointwise; gh carried from prev P2) ----
    {
      float r = RCP(1.f + EXP2(-K1 * (mR0*d0 + mR1*d1 + cRt + ghr)));
      float z = RCP(1.f + EXP2(-K1 * (mZ0*d0 + mZ1*d1 + cZt + ghz)));
      float xn = mN0*d0 + mN1*d1 + cN0 + r * (ghn + bN);
      float n = 1.f - 2.f * RCP(EXP2(K2 * xn) + 1.f);   // tanh(xn)
      hreg = (1.f - z) * n + z * hreg;
      if (o == 0) h_lds[PADH(g)] = hreg;
    }
    __syncthreads();                                   // A
    // ---- P2: u3 = W3@h  +  next-step gh = whh@h (fused reads) ----
    {
      float u3 = 0.f, sr = 0.f, sz = 0.f, sn = 0.f;
#pragma unroll
      for (int k4 = 0; k4 < 4; ++k4) {
        float4 hv = *(const float4*)&h_lds[o * 20 + k4 * 4];
        int k = k4 * 4;
        u3 += w3r[k]*hv.x + w3r[k+1]*hv.y + w3r[k+2]*hv.z + w3r[k+3]*hv.w;
        sr += wr0[k]*hv.x + wr0[k+1]*hv.y + wr0[k+2]*hv.z + wr0[k+3]*hv.w;
        sz += wr1[k]*hv.x + wr1[k+1]*hv.y + wr1[k+2]*hv.z + wr1[k+3]*hv.w;
        sn += wr2[k]*hv.x + wr2[k+1]*hv.y + wr2[k+2]*hv.z + wr2[k+3]*hv.w;
      }
      ghr = sum8(sr); ghz = sum8(sz); ghn = sum8(sn);
      u3 = sum8(u3);
      if (o == 0) u3f[SW(g)] = EXP2(K2 * u3);
    }
    __syncthreads();                                   // B
    // ---- P3: a[s] = cav - sum_h av2[h]*rcp(EA[h,s]*F3[h]+1) ----
    {
      float acc = cav;
#pragma unroll
      for (int i = 0; i < 8; ++i) {
        int sw = SW(hg * 8 + i);
        acc -= av2s[sw] * RCP(pa[i] * u3f[sw] + 1.f);
      }
      acc = sum16(acc);
      if (hg == 0) a_lds[s] = acc;
    }
    __syncthreads();                                   // C
    // ---- P4: softmax (wave-redundant) + u2 = Q@attns ----
    {
      float a = a_lds[lane];
      float m = max64(a);
      float e = EXP2(K1 * (a - m));
      float p = 0.f;
#pragma unroll
      for (int i = 0; i < 8; ++i) p += qr[i] * __shfl(e, o * 8 + i);
      float sum = sum64(e);           // issued after gathers (independent)
      p *= RCP(sum);
      p = sum8(p);
      if (o == 0) u2f[SW(g)] = EXP2(K2 * p);
    }
    __syncthreads();                                   // D
    // ---- P5: l[s] = cpv - sum_h pv2[h]*rcp(EP[h,s]*F2[h]+1) ----
    {
      float acc = cpv;
#pragma unroll
      for (int i = 0; i < 8; ++i) {
        int sw = SW(hg * 8 + i);
        acc -= pv2s[sw] * RCP(pp[i] * u2f[sw] + 1.f);
      }
      acc = sum16(acc);
      if (hg == 0) l_lds[s] = acc;
    }
    __syncthreads();                                   // E
    // ---- P6: argmax (first-index tiebreak) + logp + dec feedback ----
    {
      float L = l_lds[lane];
      float v = L;
      int idx = lane;
#define AMX(CTRL) { float ov = dppf<CTRL>(v); int oi = dppi<CTRL>(idx); \
      if (ov > v || (ov == v && oi < idx)) { v = ov; idx = oi; } }
      AMX(0xB1) AMX(0x4E) AMX(0x141) AMX(0x128)
#undef AMX
      { float ov = __shfl_xor(v, 16); int oi = __shfl_xor(idx, 16);
        if (ov > v || (ov == v && oi < idx)) { v = ov; idx = oi; } }
      { float ov = __shfl_xor(v, 32); int oi = __shfl_xor(idx, 32);
        if (ov > v || (ov == v && oi < idx)) { v = ov; idx = oi; } }
      float e2 = EXP2(K1 * (L - v));
      float s3 = sum64(e2);
      if (t == 0) {
        out[b * 64 + step] = (float)idx;                       // tour_idx
        out[8192 + b * 64 + step] = -LN2 * __builtin_amdgcn_logf(s3);  // logp
      }
      d0 = stt[idx];                                   // uniform broadcast
      d1 = stt[64 + idx];
    }
    // no barrier: next write of each buffer is >=2 barriers downstream
  }
}

extern "C" void kernel_launch(void* const* d_in, const int* in_sizes, int n_in,
                              void* d_out, int out_size, void* d_ws, size_t ws_size,
                              hipStream_t stream) {
  const float* statics  = (const float*)d_in[0];
  const float* dynamics = (const float*)d_in[1];
  const float* x0       = (const float*)d_in[2];
  const float* sw       = (const float*)d_in[3];
  const float* sb       = (const float*)d_in[4];
  const float* dw       = (const float*)d_in[5];
  const float* db       = (const float*)d_in[6];
  const float* decw     = (const float*)d_in[7];
  const float* decb     = (const float*)d_in[8];
  const float* wih      = (const float*)d_in[9];
  const float* whh      = (const float*)d_in[10];
  const float* bih      = (const float*)d_in[11];
  const float* bhh      = (const float*)d_in[12];
  const float* attn_v   = (const float*)d_in[13];
  const float* attn_W   = (const float*)d_in[14];
  const float* ptr_v    = (const float*)d_in[15];
  const float* ptr_W    = (const float*)d_in[16];
  float* ws  = (float*)d_ws;
  float* out = (float*)d_out;

  hipLaunchKernelGGL(prep_small, dim3(2), dim3(256), 0, stream,
                     wih, decw, decb, bih, ws);
  hipLaunchKernelGGL(prep_big, dim3(1024), dim3(256), 0, stream,
                     statics, dynamics, sw, sb, dw, db, attn_W, ptr_W, ws);
  hipLaunchKernelGGL(drl4tsp_main, dim3(128), dim3(1024), 0, stream,
                     statics, x0, whh, attn_W, bhh, attn_v, ptr_v, ws, out);
}

// Round 7
// 287.275 us; speedup vs baseline: 1.2212x; 1.2212x over previous
//
#include <hip/hip_runtime.h>
#include <math.h>

// Problem dims (fixed): B=128, S=64, H=128, STATIC=DYNAMIC=2
// Outputs: tour_idx [B,S] (as f32), tour_logp [B,S] -> d_out 16384 f32

#define K1  1.44269504088896340736f   // log2(e)
#define K2  2.88539008177792681472f   // 2*log2(e)
#define LN2 0.69314718055994530942f

// ---------------- ws layout (float offsets) ----------------
#define WS_M     0                       // [384][2]   M = wih @ decoder_w
#define WS_C     768                     // [384]      c = wih @ decoder_b + bih
#define WS_PREA  1152                    // [B][128][64] EA = exp2(K2*(W1@sh + W2@dh))
#define WS_PREP  (WS_PREA + 128*8192)    // [B][128][64] EP = exp2(K2*(P1@sh))
#define WS_Q     (WS_PREP + 128*8192)    // [B][128][64] Q  = P2@sh

// LDS swizzle for 128-vectors read at h = hg*16+i (8 hg-groups): stride-18
// pattern -> 8 distinct banks per instr, same-addr broadcast across s-lanes.
#define SW(h)   ((h) + ((h) >> 3))

// ---- DPP cross-lane (VALU-speed) ----
template <int CTRL>
__device__ __forceinline__ float dppf(float x) {
  int xi = __builtin_bit_cast(int, x);
  return __builtin_bit_cast(float,
      __builtin_amdgcn_update_dpp(xi, xi, CTRL, 0xF, 0xF, false));
}
template <int CTRL>
__device__ __forceinline__ int dppi(int x) {
  return __builtin_amdgcn_update_dpp(x, x, CTRL, 0xF, 0xF, false);
}
// 0xB1=quad xor1, 0x4E=quad xor2, 0x141=row_half_mirror, 0x128=row_ror:8
__device__ __forceinline__ float sum4(float x) {   // 4-lane quad
  x += dppf<0xB1>(x); x += dppf<0x4E>(x); return x;
}
__device__ __forceinline__ float sum8(float x) {   // 8 consecutive lanes
  x += dppf<0xB1>(x); x += dppf<0x4E>(x); x += dppf<0x141>(x); return x;
}
__device__ __forceinline__ float sum16(float x) {
  x += dppf<0xB1>(x); x += dppf<0x4E>(x); x += dppf<0x141>(x); x += dppf<0x128>(x);
  return x;
}
__device__ __forceinline__ float sum64(float x) {
  x = sum16(x); x += __shfl_xor(x, 16); x += __shfl_xor(x, 32); return x;
}
__device__ __forceinline__ float max64(float x) {
  x = fmaxf(x, dppf<0xB1>(x)); x = fmaxf(x, dppf<0x4E>(x));
  x = fmaxf(x, dppf<0x141>(x)); x = fmaxf(x, dppf<0x128>(x));
  x = fmaxf(x, __shfl_xor(x, 16)); x = fmaxf(x, __shfl_xor(x, 32)); return x;
}
#define RCP(x)  __builtin_amdgcn_rcpf(x)
#define EXP2(x) __builtin_amdgcn_exp2f(x)

// ---------------- tiny precompute: GRU input-path folding ----------------
__global__ __launch_bounds__(256) void prep_small(
    const float* __restrict__ wih, const float* __restrict__ decw,
    const float* __restrict__ decb, const float* __restrict__ bih,
    float* __restrict__ ws) {
  int gid = blockIdx.x * 256 + threadIdx.x;
  if (gid < 384) {
    float m0 = 0.f, m1 = 0.f, cc = 0.f;
    for (int k = 0; k < 128; ++k) {
      float w = wih[gid * 128 + k];
      m0 += w * decw[k * 2 + 0];
      m1 += w * decw[k * 2 + 1];
      cc += w * decb[k];
    }
    ws[WS_M + gid * 2 + 0] = m0;
    ws[WS_M + gid * 2 + 1] = m1;
    ws[WS_C + gid] = cc + bih[gid];
  }
}

// ---------------- big precompute: EA / EP / Q per batch ------------------
__global__ __launch_bounds__(256) void prep_big(
    const float* __restrict__ statics, const float* __restrict__ dynamics,
    const float* __restrict__ sw, const float* __restrict__ sb,
    const float* __restrict__ dw, const float* __restrict__ db,
    const float* __restrict__ attn_W, const float* __restrict__ ptr_W,
    float* __restrict__ ws) {
  __shared__ __align__(16) float sh[128 * 64];
  __shared__ __align__(16) float dh[128 * 64];
  __shared__ float st[128];
  __shared__ float dy[128];
  int b = blockIdx.x >> 3;
  int hq = blockIdx.x & 7;
  int t = threadIdx.x;
  if (t < 128) st[t] = statics[b * 128 + t];
  else         dy[t - 128] = dynamics[b * 128 + (t - 128)];
  __syncthreads();
  for (int e = t; e < 8192; e += 256) {
    int h = e >> 6, s = e & 63;
    sh[e] = sw[h * 2 + 0] * st[s] + sw[h * 2 + 1] * st[64 + s] + sb[h];
    dh[e] = dw[h * 2 + 0] * dy[s] + dw[h * 2 + 1] * dy[64 + s] + db[h];
  }
  __syncthreads();
  int hh = hq * 16 + (t >> 4);
  int s0 = (t & 15) * 4;
  float4 pA = {0, 0, 0, 0}, pP = {0, 0, 0, 0}, qq = {0, 0, 0, 0};
  for (int k = 0; k < 128; ++k) {
    float4 sv = *(const float4*)&sh[k * 64 + s0];
    float4 dv = *(const float4*)&dh[k * 64 + s0];
    float w1 = attn_W[hh * 384 + k];
    float w2 = attn_W[hh * 384 + 128 + k];
    float p1 = ptr_W[hh * 256 + k];
    float p2 = ptr_W[hh * 256 + 128 + k];
    pA.x += w1 * sv.x + w2 * dv.x;  pA.y += w1 * sv.y + w2 * dv.y;
    pA.z += w1 * sv.z + w2 * dv.z;  pA.w += w1 * sv.w + w2 * dv.w;
    pP.x += p1 * sv.x;  pP.y += p1 * sv.y;  pP.z += p1 * sv.z;  pP.w += p1 * sv.w;
    qq.x += p2 * sv.x;  qq.y += p2 * sv.y;  qq.z += p2 * sv.z;  qq.w += p2 * sv.w;
  }
  // store exp-transformed score bases (shared-exp tanh trick)
  float4 eA, eP;
  eA.x = exp2f(K2 * pA.x); eA.y = exp2f(K2 * pA.y);
  eA.z = exp2f(K2 * pA.z); eA.w = exp2f(K2 * pA.w);
  eP.x = exp2f(K2 * pP.x); eP.y = exp2f(K2 * pP.y);
  eP.z = exp2f(K2 * pP.z); eP.w = exp2f(K2 * pP.w);
  int o = b * 8192 + hh * 64 + s0;
  *(float4*)&ws[WS_PREA + o] = eA;
  *(float4*)&ws[WS_PREP + o] = eP;
  *(float4*)&ws[WS_Q + o]    = qq;
}

// ---------------- main recurrence: 1 block/batch, 512 thr, 64 steps -----
// 512 threads (the shape with a PROVEN 128-VGPR grant; 1024 thr is pinned
// at 64 VGPR by the toolchain — rounds 4-6).  Per-thread live set: whh rows
// (96f) + Q row (16f) + ~18 scalars = ~130 <= grant.  Everything else in
// LDS (~138 KB of 160): W3 bank-swizzled, EA/EP XOR-s layout.
__global__ __launch_bounds__(512)
__attribute__((amdgpu_waves_per_eu(2)))
void drl4tsp_main(
    const float* __restrict__ statics, const float* __restrict__ x0,
    const float* __restrict__ whh, const float* __restrict__ attn_W,
    const float* __restrict__ bhh_g, const float* __restrict__ attn_v,
    const float* __restrict__ ptr_v, const float* __restrict__ ws,
    float* __restrict__ out) {
  __shared__ __align__(16) float W3s[16384];  // [g][ (k4+g)&31 ]*4 swizzle
  __shared__ float EAs[8192];                 // [h][ s ^ (hg<<3) ]
  __shared__ float EPs[8192];
  __shared__ float gp[128 * 12];              // per-row GRU gate params
  __shared__ __align__(16) float h_lds[128];
  __shared__ float u3f[144];                  // SW: exp2(K2*u3[h])
  __shared__ float u2f[144];                  // SW: exp2(K2*u2[h])
  __shared__ float av2s[144];                 // SW: 2*attn_v
  __shared__ float pv2s[144];                 // SW: 2*ptr_v
  __shared__ float a_lds[64];
  __shared__ float l_lds[64];
  __shared__ float stt[128];

  const int b    = blockIdx.x;
  const int t    = threadIdx.x;
  const int lane = t & 63;
  const int g    = t >> 2;   // 0..127 row (matvec map, 4-lane groups)
  const int q    = t & 3;    // k/s quarter
  const int s    = t >> 3;   // 0..63 column (score map, 8-lane groups)
  const int hg   = t & 7;    // h-group of 16

  // ---- register-resident: whh rows (96f) + Q row (16f) ----
  float wr0[32], wr1[32], wr2[32];
  {
    const float4* pr = (const float4*)(whh + g * 128 + q * 32);
    const float4* pz = (const float4*)(whh + (128 + g) * 128 + q * 32);
    const float4* pn = (const float4*)(whh + (256 + g) * 128 + q * 32);
#pragma unroll
    for (int i = 0; i < 8; ++i) {
      float4 a = pr[i], c = pz[i], d = pn[i];
      wr0[4*i] = a.x; wr0[4*i+1] = a.y; wr0[4*i+2] = a.z; wr0[4*i+3] = a.w;
      wr1[4*i] = c.x; wr1[4*i+1] = c.y; wr1[4*i+2] = c.z; wr1[4*i+3] = c.w;
      wr2[4*i] = d.x; wr2[4*i+1] = d.y; wr2[4*i+2] = d.z; wr2[4*i+3] = d.w;
    }
  }
  float qr[16];
  {
    const float4* pq = (const float4*)(ws + WS_Q + b * 8192 + g * 64 + q * 16);
#pragma unroll
    for (int i = 0; i < 4; ++i) {
      float4 v = pq[i];
      qr[4*i] = v.x; qr[4*i+1] = v.y; qr[4*i+2] = v.z; qr[4*i+3] = v.w;
    }
  }

  // ---- LDS init ----
  {  // W3 rows, bank-swizzled on 16B granules
    const float4* src = (const float4*)(attn_W + g * 384 + 256 + q * 32);
#pragma unroll
    for (int kk = 0; kk < 8; ++kk) {
      int k4 = q * 8 + kk;
      *(float4*)&W3s[g * 128 + ((k4 + g) & 31) * 4] = src[kk];
    }
  }
  for (int e = t; e < 8192; e += 512) {  // EA/EP with XOR-s layout
    int h = e >> 6, sE = e & 63;
    int idx = (h << 6) | (sE ^ ((h >> 4) << 3));
    EAs[idx] = ws[WS_PREA + b * 8192 + e];
    EPs[idx] = ws[WS_PREP + b * 8192 + e];
  }
  const float* Mm = ws + WS_M;
  const float* Cc = ws + WS_C;
  if (t < 128) {
    int gg = t;
    gp[gg*12 + 0] = Mm[gg*2];         gp[gg*12 + 1] = Mm[gg*2 + 1];
    gp[gg*12 + 2] = Cc[gg] + bhh_g[gg];
    gp[gg*12 + 3] = Mm[(128+gg)*2];   gp[gg*12 + 4] = Mm[(128+gg)*2 + 1];
    gp[gg*12 + 5] = Cc[128+gg] + bhh_g[128+gg];
    gp[gg*12 + 6] = Mm[(256+gg)*2];   gp[gg*12 + 7] = Mm[(256+gg)*2 + 1];
    gp[gg*12 + 8] = Cc[256+gg];       gp[gg*12 + 9] = bhh_g[256+gg];
    stt[gg] = statics[b * 128 + gg];
    av2s[SW(gg)] = 2.0f * attn_v[gg];
    pv2s[SW(gg)] = 2.0f * ptr_v[gg];
  }
  float cav = 0.f, cpv = 0.f;
#pragma unroll
  for (int i = 0; i < 16; ++i) {
    cav += attn_v[hg * 16 + i];
    cpv += ptr_v[hg * 16 + i];
  }
  __syncthreads();

  float hreg = 0.f, ghr = 0.f, ghz = 0.f, ghn = 0.f;
  float d0 = x0[0], d1 = x0[1];

  for (int step = 0; step < 64; ++step) {
    // ---- P1: GRU gates (pointwise; gh carried from prev P2) ----
    {
      const float* gpr = &gp[g * 12];
      float r = RCP(1.f + EXP2(-K1 * (gpr[0]*d0 + gpr[1]*d1 + gpr[2] + ghr)));
      float z = RCP(1.f + EXP2(-K1 * (gpr[3]*d0 + gpr[4]*d1 + gpr[5] + ghz)));
      float xn = gpr[6]*d0 + gpr[7]*d1 + gpr[8] + r * (ghn + gpr[9]);
      float n = 1.f - 2.f * RCP(EXP2(K2 * xn) + 1.f);   // tanh(xn)
      hreg = (1.f - z) * n + z * hreg;
      if (q == 0) h_lds[g] = hreg;
    }
    __syncthreads();                                   // A
    // ---- P2: u3 = W3@h (LDS weights) + next gh = whh@h (reg weights) ---
    {
      float u3 = 0.f, sr = 0.f, sz = 0.f, sn = 0.f;
#pragma unroll
      for (int kk = 0; kk < 8; ++kk) {
        float4 hv = *(const float4*)&h_lds[q * 32 + kk * 4];
        float4 wv = *(const float4*)&W3s[g * 128 + ((q*8 + kk + g) & 31) * 4];
        int k = kk * 4;
        u3 += wv.x*hv.x + wv.y*hv.y + wv.z*hv.z + wv.w*hv.w;
        sr += wr0[k]*hv.x + wr0[k+1]*hv.y + wr0[k+2]*hv.z + wr0[k+3]*hv.w;
        sz += wr1[k]*hv.x + wr1[k+1]*hv.y + wr1[k+2]*hv.z + wr1[k+3]*hv.w;
        sn += wr2[k]*hv.x + wr2[k+1]*hv.y + wr2[k+2]*hv.z + wr2[k+3]*hv.w;
      }
      ghr = sum4(sr); ghz = sum4(sz); ghn = sum4(sn);
      u3 = sum4(u3);
      if (q == 0) u3f[SW(g)] = EXP2(K2 * u3);
    }
    __syncthreads();                                   // B
    // ---- P3: a[s] = cav - sum_h av2[h]*rcp(EA[h,s]*F3[h]+1) ----
    {
      float acc = cav;
      int sx = s ^ (hg << 3);
#pragma unroll
      for (int i = 0; i < 16; ++i) {
        int h = hg * 16 + i;
        acc -= av2s[SW(h)] * RCP(EAs[(h << 6) | sx] * u3f[SW(h)] + 1.f);
      }
      acc = sum8(acc);
      if (hg == 0) a_lds[s] = acc;
    }
    __syncthreads();                                   // C
    // ---- P4: softmax (wave-redundant) + u2 = Q@attns ----
    {
      float a = a_lds[lane];
      float m = max64(a);
      float e = EXP2(K1 * (a - m));
      float p = 0.f;
#pragma unroll
      for (int i = 0; i < 16; ++i) p += qr[i] * __shfl(e, q * 16 + i);
      float sum = sum64(e);
      p *= RCP(sum);
      p = sum4(p);
      if (q == 0) u2f[SW(g)] = EXP2(K2 * p);
    }
    __syncthreads();                                   // D
    // ---- P5: l[s] = cpv - sum_h pv2[h]*rcp(EP[h,s]*F2[h]+1) ----
    {
      float acc = cpv;
      int sx = s ^ (hg << 3);
#pragma unroll
      for (int i = 0; i < 16; ++i) {
        int h = hg * 16 + i;
        acc -= pv2s[SW(h)] * RCP(EPs[(h << 6) | sx] * u2f[SW(h)] + 1.f);
      }
      acc = sum8(acc);
      if (hg == 0) l_lds[s] = acc;
    }
    __syncthreads();                                   // E
    // ---- P6: argmax (first-index tiebreak) + logp + dec feedback ----
    {
      float L = l_lds[lane];
      float v = L;
      int idx = lane;
#define AMX(CTRL) { float ov = dppf<CTRL>(v); int oi = dppi<CTRL>(idx); \
      if (ov > v || (ov == v && oi < idx)) { v = ov; idx = oi; } }
      AMX(0xB1) AMX(0x4E) AMX(0x141) AMX(0x128)
#undef AMX
      { float ov = __shfl_xor(v, 16); int oi = __shfl_xor(idx, 16);
        if (ov > v || (ov == v && oi < idx)) { v = ov; idx = oi; } }
      { float ov = __shfl_xor(v, 32); int oi = __shfl_xor(idx, 32);
        if (ov > v || (ov == v && oi < idx)) { v = ov; idx = oi; } }
      float e2 = EXP2(K1 * (L - v));
      float s3 = sum64(e2);
      if (t == 0) {
        out[b * 64 + step] = (float)idx;                       // tour_idx
        out[8192 + b * 64 + step] = -LN2 * __builtin_amdgcn_logf(s3);  // logp
      }
      d0 = stt[idx];                                   // uniform broadcast
      d1 = stt[64 + idx];
    }
    // no barrier: every buffer's next write is >=2 barrier-phases away
  }
}

extern "C" void kernel_launch(void* const* d_in, const int* in_sizes, int n_in,
                              void* d_out, int out_size, void* d_ws, size_t ws_size,
                              hipStream_t stream) {
  const float* statics  = (const float*)d_in[0];
  const float* dynamics = (const float*)d_in[1];
  const float* x0       = (const float*)d_in[2];
  const float* sw       = (const float*)d_in[3];
  const float* sb       = (const float*)d_in[4];
  const float* dw       = (const float*)d_in[5];
  const float* db       = (const float*)d_in[6];
  const float* decw     = (const float*)d_in[7];
  const float* decb     = (const float*)d_in[8];
  const float* wih      = (const float*)d_in[9];
  const float* whh      = (const float*)d_in[10];
  const float* bih      = (const float*)d_in[11];
  const float* bhh      = (const float*)d_in[12];
  const float* attn_v   = (const float*)d_in[13];
  const float* attn_W   = (const float*)d_in[14];
  const float* ptr_v    = (const float*)d_in[15];
  const float* ptr_W    = (const float*)d_in[16];
  float* ws  = (float*)d_ws;
  float* out = (float*)d_out;

  hipLaunchKernelGGL(prep_small, dim3(2), dim3(256), 0, stream,
                     wih, decw, decb, bih, ws);
  hipLaunchKernelGGL(prep_big, dim3(1024), dim3(256), 0, stream,
                     statics, dynamics, sw, sb, dw, db, attn_W, ptr_W, ws);
  hipLaunchKernelGGL(drl4tsp_main, dim3(128), dim3(512), 0, stream,
                     statics, x0, whh, attn_W, bhh, attn_v, ptr_v, ws, out);
}

// Round 8
// 226.036 us; speedup vs baseline: 1.5521x; 1.2709x over previous
//
#include <hip/hip_runtime.h>
#include <math.h>

// Problem dims (fixed): B=128, S=64, H=128, STATIC=DYNAMIC=2
// Outputs: tour_idx [B,S] (as f32), tour_logp [B,S] -> d_out 16384 f32

#define K1  1.44269504088896340736f   // log2(e)
#define K2  2.88539008177792681472f   // 2*log2(e)
#define LN2 0.69314718055994530942f

// ---------------- ws layout (float offsets) ----------------
#define WS_M     0                       // [384][2]   M = wih @ decoder_w
#define WS_C     768                     // [384]      c = wih @ decoder_b + bih
#define WS_PREA  1152                    // [B][128][64] EA = exp2(K2*(W1@sh + W2@dh))
#define WS_PREP  (WS_PREA + 128*8192)    // [B][128][64] EP = exp2(K2*(P1@sh))
#define WS_Q     (WS_PREP + 128*8192)    // [B][128][64] Q  = P2@sh

// ---- DPP cross-lane (VALU-speed) ----
template <int CTRL>
__device__ __forceinline__ float dppf(float x) {
  int xi = __builtin_bit_cast(int, x);
  return __builtin_bit_cast(float,
      __builtin_amdgcn_update_dpp(xi, xi, CTRL, 0xF, 0xF, false));
}
template <int CTRL>
__device__ __forceinline__ int dppi(int x) {
  return __builtin_amdgcn_update_dpp(x, x, CTRL, 0xF, 0xF, false);
}
// 0xB1=quad xor1, 0x4E=quad xor2, 0x141=row_half_mirror, 0x128=row_ror:8
__device__ __forceinline__ float sum4(float x) {
  x += dppf<0xB1>(x); x += dppf<0x4E>(x); return x;
}
__device__ __forceinline__ float sum8(float x) {
  x += dppf<0xB1>(x); x += dppf<0x4E>(x); x += dppf<0x141>(x); return x;
}
__device__ __forceinline__ float sum16(float x) {
  x += dppf<0xB1>(x); x += dppf<0x4E>(x); x += dppf<0x141>(x); x += dppf<0x128>(x);
  return x;
}
__device__ __forceinline__ float sum64(float x) {
  x = sum16(x); x += __shfl_xor(x, 16); x += __shfl_xor(x, 32); return x;
}
__device__ __forceinline__ float max64(float x) {
  x = fmaxf(x, dppf<0xB1>(x)); x = fmaxf(x, dppf<0x4E>(x));
  x = fmaxf(x, dppf<0x141>(x)); x = fmaxf(x, dppf<0x128>(x));
  x = fmaxf(x, __shfl_xor(x, 16)); x = fmaxf(x, __shfl_xor(x, 32)); return x;
}
#define RCP(x)  __builtin_amdgcn_rcpf(x)
#define EXP2(x) __builtin_amdgcn_exp2f(x)

// bijective bank-rotation for pair-granule index p (8 granules per stripe):
// keep stripe (p&56), rotate position by stripe id (p>>3).
__device__ __forceinline__ int rot8(int p) {
  return (p & 56) | ((p + (p >> 3)) & 7);
}

// ---------------- tiny precompute: GRU input-path folding ----------------
__global__ __launch_bounds__(256) void prep_small(
    const float* __restrict__ wih, const float* __restrict__ decw,
    const float* __restrict__ decb, const float* __restrict__ bih,
    float* __restrict__ ws) {
  int gid = blockIdx.x * 256 + threadIdx.x;
  if (gid < 384) {
    float m0 = 0.f, m1 = 0.f, cc = 0.f;
    for (int k = 0; k < 128; ++k) {
      float w = wih[gid * 128 + k];
      m0 += w * decw[k * 2 + 0];
      m1 += w * decw[k * 2 + 1];
      cc += w * decb[k];
    }
    ws[WS_M + gid * 2 + 0] = m0;
    ws[WS_M + gid * 2 + 1] = m1;
    ws[WS_C + gid] = cc + bih[gid];
  }
}

// ---------------- big precompute: EA / EP / Q per batch ------------------
__global__ __launch_bounds__(256) void prep_big(
    const float* __restrict__ statics, const float* __restrict__ dynamics,
    const float* __restrict__ sw, const float* __restrict__ sb,
    const float* __restrict__ dw, const float* __restrict__ db,
    const float* __restrict__ attn_W, const float* __restrict__ ptr_W,
    float* __restrict__ ws) {
  __shared__ __align__(16) float sh[128 * 64];
  __shared__ __align__(16) float dh[128 * 64];
  __shared__ float st[128];
  __shared__ float dy[128];
  int b = blockIdx.x >> 3;
  int hq = blockIdx.x & 7;
  int t = threadIdx.x;
  if (t < 128) st[t] = statics[b * 128 + t];
  else         dy[t - 128] = dynamics[b * 128 + (t - 128)];
  __syncthreads();
  for (int e = t; e < 8192; e += 256) {
    int h = e >> 6, s = e & 63;
    sh[e] = sw[h * 2 + 0] * st[s] + sw[h * 2 + 1] * st[64 + s] + sb[h];
    dh[e] = dw[h * 2 + 0] * dy[s] + dw[h * 2 + 1] * dy[64 + s] + db[h];
  }
  __syncthreads();
  int hh = hq * 16 + (t >> 4);
  int s0 = (t & 15) * 4;
  float4 pA = {0, 0, 0, 0}, pP = {0, 0, 0, 0}, qq = {0, 0, 0, 0};
  for (int k = 0; k < 128; ++k) {
    float4 sv = *(const float4*)&sh[k * 64 + s0];
    float4 dv = *(const float4*)&dh[k * 64 + s0];
    float w1 = attn_W[hh * 384 + k];
    float w2 = attn_W[hh * 384 + 128 + k];
    float p1 = ptr_W[hh * 256 + k];
    float p2 = ptr_W[hh * 256 + 128 + k];
    pA.x += w1 * sv.x + w2 * dv.x;  pA.y += w1 * sv.y + w2 * dv.y;
    pA.z += w1 * sv.z + w2 * dv.z;  pA.w += w1 * sv.w + w2 * dv.w;
    pP.x += p1 * sv.x;  pP.y += p1 * sv.y;  pP.z += p1 * sv.z;  pP.w += p1 * sv.w;
    qq.x += p2 * sv.x;  qq.y += p2 * sv.y;  qq.z += p2 * sv.z;  qq.w += p2 * sv.w;
  }
  // store exp-transformed score bases (shared-exp tanh trick)
  float4 eA, eP;
  eA.x = exp2f(K2 * pA.x); eA.y = exp2f(K2 * pA.y);
  eA.z = exp2f(K2 * pA.z); eA.w = exp2f(K2 * pA.w);
  eP.x = exp2f(K2 * pP.x); eP.y = exp2f(K2 * pP.y);
  eP.z = exp2f(K2 * pP.z); eP.w = exp2f(K2 * pP.w);
  int o = b * 8192 + hh * 64 + s0;
  *(float4*)&ws[WS_PREA + o] = eA;
  *(float4*)&ws[WS_PREP + o] = eP;
  *(float4*)&ws[WS_Q + o]    = qq;
}

// ---------------- main recurrence: 1 block/batch, 512 thr, 64 steps -----
// whh (96f, interleaved-k) + Q (16f) in registers; W3 / EA^T / EP^T / gate
// params in LDS with position-exact rotations; all score-phase LDS reads
// are b128; softmax shift-invariance drops the Σv constants; P4 gathers via
// a shared attns buffer (benign identical writes) instead of 16 bpermutes.
__global__ __launch_bounds__(512)
void drl4tsp_main(
    const float* __restrict__ statics, const float* __restrict__ x0,
    const float* __restrict__ whh, const float* __restrict__ attn_W,
    const float* __restrict__ bhh_g, const float* __restrict__ attn_v,
    const float* __restrict__ ptr_v, const float* __restrict__ ws,
    float* __restrict__ out) {
  __shared__ float4 W3s4[128 * 32];   // 64KB [g][(j+g)&31]
  __shared__ float4 EAT4[64 * 32];    // 32KB [s][(gi+s)&31] (transposed)
  __shared__ float4 EPT4[64 * 32];    // 32KB
  __shared__ float4 uav3[64];         // {u3f[2p],av2[2p],u3f[2p+1],av2[2p+1]} @ rot8(p)
  __shared__ float4 uav2[64];         // {u2f, pv2} pairs @ rot8(p)
  __shared__ float4 gp4[128 * 3];     // 6KB gate params
  __shared__ __align__(16) float hp[144];     // h padded: [k>>5]*36 + (k&31)
  __shared__ __align__(16) float attns[64];   // shared e-buffer (redundant writes)
  __shared__ float a_lds[64];
  __shared__ float l_lds[64];
  __shared__ float stt[128];

  const int b    = blockIdx.x;
  const int t    = threadIdx.x;
  const int lane = t & 63;
  const int g    = t >> 2;   // 0..127 row (matvec map, 4-lane groups)
  const int q    = t & 3;    // k/s quarter
  const int s    = t >> 3;   // 0..63 column (score map, 8-lane groups)
  const int hg   = t & 7;    // h-group of 16

  // ---- register weights: whh rows, interleaved k-map (k = kk*16+q*4+j) ----
  float wr0[32], wr1[32], wr2[32];
#pragma unroll
  for (int kk = 0; kk < 8; ++kk) {
    float4 a = *(const float4*)(whh + g * 128         + kk * 16 + q * 4);
    float4 c = *(const float4*)(whh + (128 + g) * 128 + kk * 16 + q * 4);
    float4 d = *(const float4*)(whh + (256 + g) * 128 + kk * 16 + q * 4);
    wr0[4*kk] = a.x; wr0[4*kk+1] = a.y; wr0[4*kk+2] = a.z; wr0[4*kk+3] = a.w;
    wr1[4*kk] = c.x; wr1[4*kk+1] = c.y; wr1[4*kk+2] = c.z; wr1[4*kk+3] = c.w;
    wr2[4*kk] = d.x; wr2[4*kk+1] = d.y; wr2[4*kk+2] = d.z; wr2[4*kk+3] = d.w;
  }
  float qr[16];
  {
    const float4* pq = (const float4*)(ws + WS_Q + b * 8192 + g * 64 + q * 16);
#pragma unroll
    for (int i = 0; i < 4; ++i) {
      float4 v = pq[i];
      qr[4*i] = v.x; qr[4*i+1] = v.y; qr[4*i+2] = v.z; qr[4*i+3] = v.w;
    }
  }

  // ---- LDS init ----
  {  // W3 row g, granule j stored at (j+g)&31
    const float4* src = (const float4*)(attn_W + g * 384 + 256);
#pragma unroll
    for (int kk = 0; kk < 8; ++kk) {
      int j = q * 8 + kk;
      W3s4[g * 32 + ((j + g) & 31)] = src[j];
    }
  }
  for (int e = t; e < 8192; e += 512) {  // EA/EP transpose + s-rotation
    int h = e >> 6, sE = e & 63;
    int rg = ((h >> 2) + sE) & 31;
    ((float*)EAT4)[sE * 128 + rg * 4 + (h & 3)] = ws[WS_PREA + b * 8192 + e];
    ((float*)EPT4)[sE * 128 + rg * 4 + (h & 3)] = ws[WS_PREP + b * 8192 + e];
  }
  if (t < 128) {
    int h = t;
    int rg = rot8(h >> 1);
    ((float*)uav3)[rg * 4 + (h & 1) * 2 + 1] = 2.0f * attn_v[h];
    ((float*)uav2)[rg * 4 + (h & 1) * 2 + 1] = 2.0f * ptr_v[h];
    stt[h] = statics[b * 128 + h];
    const float* Mm = ws + WS_M;
    const float* Cc = ws + WS_C;
    float cR = Cc[h] + bhh_g[h];
    float cZ = Cc[128 + h] + bhh_g[128 + h];
    gp4[h*3 + 0] = float4{Mm[h*2], Mm[h*2+1], cR, Mm[(128+h)*2]};
    gp4[h*3 + 1] = float4{Mm[(128+h)*2+1], cZ, Mm[(256+h)*2], Mm[(256+h)*2+1]};
    gp4[h*3 + 2] = float4{Cc[256+h], bhh_g[256+h], 0.f, 0.f};
  }
  __syncthreads();

  float hreg = 0.f, ghr = 0.f, ghz = 0.f, ghn = 0.f;
  float d0 = x0[0], d1 = x0[1];

  for (int step = 0; step < 64; ++step) {
    // ---- P1: GRU gates (pointwise; gh carried from prev P2) ----
    {
      float4 v0 = gp4[g*3], v1 = gp4[g*3+1], v2 = gp4[g*3+2];
      float r = RCP(1.f + EXP2(-K1 * (v0.x*d0 + v0.y*d1 + v0.z + ghr)));
      float z = RCP(1.f + EXP2(-K1 * (v0.w*d0 + v1.x*d1 + v1.y + ghz)));
      float xn = v1.z*d0 + v1.w*d1 + v2.x + r * (ghn + v2.y);
      float n = 1.f - 2.f * RCP(EXP2(K2 * xn) + 1.f);   // tanh(xn)
      hreg = (1.f - z) * n + z * hreg;
      if (q == 0) hp[(g >> 5) * 36 + (g & 31)] = hreg;
    }
    __syncthreads();                                   // A
    // ---- P2: u3 = W3@h (LDS) + next-step gh = whh@h (regs) ----
    {
      float u3 = 0.f, sr = 0.f, sz = 0.f, sn = 0.f;
#pragma unroll
      for (int kk = 0; kk < 8; ++kk) {
        // k-granule j = kk*4+q of h, padded layout
        float4 hv = *(const float4*)&hp[(kk >> 1) * 36 + (kk & 1) * 16 + q * 4];
        float4 wv = W3s4[g * 32 + ((kk * 4 + q + g) & 31)];
        int k = kk * 4;
        u3 += wv.x*hv.x + wv.y*hv.y + wv.z*hv.z + wv.w*hv.w;
        sr += wr0[k]*hv.x + wr0[k+1]*hv.y + wr0[k+2]*hv.z + wr0[k+3]*hv.w;
        sz += wr1[k]*hv.x + wr1[k+1]*hv.y + wr1[k+2]*hv.z + wr1[k+3]*hv.w;
        sn += wr2[k]*hv.x + wr2[k+1]*hv.y + wr2[k+2]*hv.z + wr2[k+3]*hv.w;
      }
      ghr = sum4(sr); ghz = sum4(sz); ghn = sum4(sn);
      u3 = sum4(u3);
      if (q == 0)
        ((float*)uav3)[rot8(g >> 1) * 4 + (g & 1) * 2] = EXP2(K2 * u3);
    }
    __syncthreads();                                   // B
    // ---- P3: a'[s] = -sum_h av2[h]*rcp(EA[h,s]*F3[h]+1)  (shift-inv.) ----
    {
      float acc = 0.f;
#pragma unroll
      for (int ii = 0; ii < 4; ++ii) {
        float4 ea = EAT4[s * 32 + ((hg * 4 + ii + s) & 31)];  // h=hg*16+ii*4..
        int p0 = hg * 8 + 2 * ii;
        float4 ua = uav3[(p0 & 56) | ((p0 + hg) & 7)];
        float4 ub = uav3[((p0+1) & 56) | ((p0 + 1 + hg) & 7)];
        acc += ua.y * RCP(ea.x * ua.x + 1.f)
             + ua.w * RCP(ea.y * ua.z + 1.f)
             + ub.y * RCP(ea.z * ub.x + 1.f)
             + ub.w * RCP(ea.w * ub.z + 1.f);
      }
      acc = sum8(acc);
      if (hg == 0) a_lds[s] = -acc;
    }
    __syncthreads();                                   // C
    // ---- P4: softmax (wave-redundant) + u2 = Q@attns ----
    {
      float a = a_lds[lane];
      float m = max64(a);
      float e = EXP2(K1 * (a - m));
      attns[lane] = e;            // identical writes from all waves: benign
      float sum = sum64(e);       // overlaps with the write latency
      float p = 0.f;
#pragma unroll
      for (int ii = 0; ii < 4; ++ii) {
        float4 av = *(const float4*)&attns[q * 16 + ii * 4];
        p += qr[4*ii]*av.x + qr[4*ii+1]*av.y + qr[4*ii+2]*av.z + qr[4*ii+3]*av.w;
      }
      p *= RCP(sum);
      p = sum4(p);
      if (q == 0)
        ((float*)uav2)[rot8(g >> 1) * 4 + (g & 1) * 2] = EXP2(K2 * p);
    }
    __syncthreads();                                   // D
    // ---- P5: l'[s] = -sum_h pv2[h]*rcp(EP[h,s]*F2[h]+1) ----
    {
      float acc = 0.f;
#pragma unroll
      for (int ii = 0; ii < 4; ++ii) {
        float4 ep = EPT4[s * 32 + ((hg * 4 + ii + s) & 31)];
        int p0 = hg * 8 + 2 * ii;
        float4 ua = uav2[(p0 & 56) | ((p0 + hg) & 7)];
        float4 ub = uav2[((p0+1) & 56) | ((p0 + 1 + hg) & 7)];
        acc += ua.y * RCP(ep.x * ua.x + 1.f)
             + ua.w * RCP(ep.y * ua.z + 1.f)
             + ub.y * RCP(ep.z * ub.x + 1.f)
             + ub.w * RCP(ep.w * ub.z + 1.f);
      }
      acc = sum8(acc);
      if (hg == 0) l_lds[s] = -acc;
    }
    __syncthreads();                                   // E
    // ---- P6: argmax (first-index tiebreak) + logp + dec feedback ----
    {
      float L = l_lds[lane];
      float v = L;
      int idx = lane;
#define AMX(CTRL) { float ov = dppf<CTRL>(v); int oi = dppi<CTRL>(idx); \
      if (ov > v || (ov == v && oi < idx)) { v = ov; idx = oi; } }
      AMX(0xB1) AMX(0x4E) AMX(0x141) AMX(0x128)
#undef AMX
      { float ov = __shfl_xor(v, 16); int oi = __shfl_xor(idx, 16);
        if (ov > v || (ov == v && oi < idx)) { v = ov; idx = oi; } }
      { float ov = __shfl_xor(v, 32); int oi = __shfl_xor(idx, 32);
        if (ov > v || (ov == v && oi < idx)) { v = ov; idx = oi; } }
      float e2 = EXP2(K1 * (L - v));
      float s3 = sum64(e2);
      if (t == 0) {
        out[b * 64 + step] = (float)idx;                       // tour_idx
        out[8192 + b * 64 + step] = -LN2 * __builtin_amdgcn_logf(s3);  // logp
      }
      d0 = stt[idx];                                   // uniform broadcast
      d1 = stt[64 + idx];
    }
    // no barrier: every buffer's next write is >=2 barrier-phases away
  }
}

extern "C" void kernel_launch(void* const* d_in, const int* in_sizes, int n_in,
                              void* d_out, int out_size, void* d_ws, size_t ws_size,
                              hipStream_t stream) {
  const float* statics  = (const float*)d_in[0];
  const float* dynamics = (const float*)d_in[1];
  const float* x0       = (const float*)d_in[2];
  const float* sw       = (const float*)d_in[3];
  const float* sb       = (const float*)d_in[4];
  const float* dw       = (const float*)d_in[5];
  const float* db       = (const float*)d_in[6];
  const float* decw     = (const float*)d_in[7];
  const float* decb     = (const float*)d_in[8];
  const float* wih      = (const float*)d_in[9];
  const float* whh      = (const float*)d_in[10];
  const float* bih      = (const float*)d_in[11];
  const float* bhh      = (const float*)d_in[12];
  const float* attn_v   = (const float*)d_in[13];
  const float* attn_W   = (const float*)d_in[14];
  const float* ptr_v    = (const float*)d_in[15];
  const float* ptr_W    = (const float*)d_in[16];
  float* ws  = (float*)d_ws;
  float* out = (float*)d_out;

  hipLaunchKernelGGL(prep_small, dim3(2), dim3(256), 0, stream,
                     wih, decw, decb, bih, ws);
  hipLaunchKernelGGL(prep_big, dim3(1024), dim3(256), 0, stream,
                     statics, dynamics, sw, sb, dw, db, attn_W, ptr_W, ws);
  hipLaunchKernelGGL(drl4tsp_main, dim3(128), dim3(512), 0, stream,
                     statics, x0, whh, attn_W, bhh, attn_v, ptr_v, ws, out);
}

// Round 9
// 217.497 us; speedup vs baseline: 1.6130x; 1.0393x over previous
//
#include <hip/hip_runtime.h>
#include <math.h>

// Problem dims (fixed): B=128, S=64, H=128, STATIC=DYNAMIC=2
// Outputs: tour_idx [B,S] (as f32), tour_logp [B,S] -> d_out 16384 f32

#define K1  1.44269504088896340736f   // log2(e)
#define K2  2.88539008177792681472f   // 2*log2(e)
#define LN2 0.69314718055994530942f

// ---------------- ws layout (float offsets) ----------------
#define WS_M     0                       // [384][2]   M = wih @ decoder_w
#define WS_C     768                     // [384]      c = wih @ decoder_b + bih
#define WS_PREA  1152                    // [B][128][64] EA = exp2(K2*(W1@sh + W2@dh))
#define WS_PREP  (WS_PREA + 128*8192)    // [B][128][64] EP = exp2(K2*(P1@sh))
#define WS_Q     (WS_PREP + 128*8192)    // [B][128][64] Q  = P2@sh

// ---- DPP cross-lane (VALU-speed) ----
template <int CTRL>
__device__ __forceinline__ float dppf(float x) {
  int xi = __builtin_bit_cast(int, x);
  return __builtin_bit_cast(float,
      __builtin_amdgcn_update_dpp(xi, xi, CTRL, 0xF, 0xF, false));
}
// 0xB1=quad xor1, 0x4E=quad xor2, 0x141=row_half_mirror, 0x128=row_ror:8
__device__ __forceinline__ float sum4(float x) {
  x += dppf<0xB1>(x); x += dppf<0x4E>(x); return x;
}
__device__ __forceinline__ float sum8(float x) {
  x += dppf<0xB1>(x); x += dppf<0x4E>(x); x += dppf<0x141>(x); return x;
}
__device__ __forceinline__ float sum16(float x) {
  x += dppf<0xB1>(x); x += dppf<0x4E>(x); x += dppf<0x141>(x); x += dppf<0x128>(x);
  return x;
}
__device__ __forceinline__ float sum64(float x) {
  x = sum16(x); x += __shfl_xor(x, 16); x += __shfl_xor(x, 32); return x;
}
__device__ __forceinline__ float max64(float x) {
  x = fmaxf(x, dppf<0xB1>(x)); x = fmaxf(x, dppf<0x4E>(x));
  x = fmaxf(x, dppf<0x141>(x)); x = fmaxf(x, dppf<0x128>(x));
  x = fmaxf(x, __shfl_xor(x, 16)); x = fmaxf(x, __shfl_xor(x, 32)); return x;
}
#define RCP(x)  __builtin_amdgcn_rcpf(x)
#define EXP2(x) __builtin_amdgcn_exp2f(x)

// bijective bank-rotation for pair-granule index p
__device__ __forceinline__ int rot8(int p) {
  return (p & 56) | ((p + (p >> 3)) & 7);
}

// ---------------- tiny precompute: GRU input-path folding ----------------
__global__ __launch_bounds__(256) void prep_small(
    const float* __restrict__ wih, const float* __restrict__ decw,
    const float* __restrict__ decb, const float* __restrict__ bih,
    float* __restrict__ ws) {
  int gid = blockIdx.x * 256 + threadIdx.x;
  if (gid < 384) {
    float m0 = 0.f, m1 = 0.f, cc = 0.f;
    for (int k = 0; k < 128; ++k) {
      float w = wih[gid * 128 + k];
      m0 += w * decw[k * 2 + 0];
      m1 += w * decw[k * 2 + 1];
      cc += w * decb[k];
    }
    ws[WS_M + gid * 2 + 0] = m0;
    ws[WS_M + gid * 2 + 1] = m1;
    ws[WS_C + gid] = cc + bih[gid];
  }
}

// ---------------- big precompute: EA / EP / Q per batch ------------------
__global__ __launch_bounds__(256) void prep_big(
    const float* __restrict__ statics, const float* __restrict__ dynamics,
    const float* __restrict__ sw, const float* __restrict__ sb,
    const float* __restrict__ dw, const float* __restrict__ db,
    const float* __restrict__ attn_W, const float* __restrict__ ptr_W,
    float* __restrict__ ws) {
  __shared__ __align__(16) float sh[128 * 64];
  __shared__ __align__(16) float dh[128 * 64];
  __shared__ float st[128];
  __shared__ float dy[128];
  int b = blockIdx.x >> 3;
  int hq = blockIdx.x & 7;
  int t = threadIdx.x;
  if (t < 128) st[t] = statics[b * 128 + t];
  else         dy[t - 128] = dynamics[b * 128 + (t - 128)];
  __syncthreads();
  for (int e = t; e < 8192; e += 256) {
    int h = e >> 6, s = e & 63;
    sh[e] = sw[h * 2 + 0] * st[s] + sw[h * 2 + 1] * st[64 + s] + sb[h];
    dh[e] = dw[h * 2 + 0] * dy[s] + dw[h * 2 + 1] * dy[64 + s] + db[h];
  }
  __syncthreads();
  int hh = hq * 16 + (t >> 4);
  int s0 = (t & 15) * 4;
  float4 pA = {0, 0, 0, 0}, pP = {0, 0, 0, 0}, qq = {0, 0, 0, 0};
  for (int k = 0; k < 128; ++k) {
    float4 sv = *(const float4*)&sh[k * 64 + s0];
    float4 dv = *(const float4*)&dh[k * 64 + s0];
    float w1 = attn_W[hh * 384 + k];
    float w2 = attn_W[hh * 384 + 128 + k];
    float p1 = ptr_W[hh * 256 + k];
    float p2 = ptr_W[hh * 256 + 128 + k];
    pA.x += w1 * sv.x + w2 * dv.x;  pA.y += w1 * sv.y + w2 * dv.y;
    pA.z += w1 * sv.z + w2 * dv.z;  pA.w += w1 * sv.w + w2 * dv.w;
    pP.x += p1 * sv.x;  pP.y += p1 * sv.y;  pP.z += p1 * sv.z;  pP.w += p1 * sv.w;
    qq.x += p2 * sv.x;  qq.y += p2 * sv.y;  qq.z += p2 * sv.z;  qq.w += p2 * sv.w;
  }
  // store exp-transformed score bases (shared-exp tanh trick)
  float4 eA, eP;
  eA.x = exp2f(K2 * pA.x); eA.y = exp2f(K2 * pA.y);
  eA.z = exp2f(K2 * pA.z); eA.w = exp2f(K2 * pA.w);
  eP.x = exp2f(K2 * pP.x); eP.y = exp2f(K2 * pP.y);
  eP.z = exp2f(K2 * pP.z); eP.w = exp2f(K2 * pP.w);
  int o = b * 8192 + hh * 64 + s0;
  *(float4*)&ws[WS_PREA + o] = eA;
  *(float4*)&ws[WS_PREP + o] = eP;
  *(float4*)&ws[WS_Q + o]    = qq;
}

// ---------------- main recurrence: 1 block/batch, 512 thr, 64 steps -----
// Rebalanced phases: gh matvec split into P3/P4 windows (fills trans/LDS
// stalls); no max-subtraction in P4 softmax (shift-invariant, range-safe);
// P6 argmax via fmax-chain + ballot/ctz (exact first-index tiebreak).
__global__ __launch_bounds__(512)
__attribute__((amdgpu_waves_per_eu(2)))
void drl4tsp_main(
    const float* __restrict__ statics, const float* __restrict__ x0,
    const float* __restrict__ whh, const float* __restrict__ attn_W,
    const float* __restrict__ bhh_g, const float* __restrict__ attn_v,
    const float* __restrict__ ptr_v, const float* __restrict__ ws,
    float* __restrict__ out) {
  __shared__ float4 W3s4[128 * 32];   // 64KB [g][(j+g)&31]
  __shared__ float4 EAT4[64 * 32];    // 32KB [s][(gi+s)&31] (transposed)
  __shared__ float4 EPT4[64 * 32];    // 32KB
  __shared__ float4 uav3[64];         // {u3f[2p],av2[2p],u3f[2p+1],av2[2p+1]} @ rot8(p)
  __shared__ float4 uav2[64];         // {u2f, pv2} pairs @ rot8(p)
  __shared__ float4 gp4[128 * 3];     // 6KB gate params
  __shared__ __align__(16) float hp[144];     // h padded: [k>>5]*36 + (k&31)
  __shared__ __align__(16) float attns[64];   // shared e-buffer (redundant writes)
  __shared__ float a_lds[64];
  __shared__ float l_lds[64];
  __shared__ float stt[128];

  const int b    = blockIdx.x;
  const int t    = threadIdx.x;
  const int lane = t & 63;
  const int g    = t >> 2;   // 0..127 row (matvec map, 4-lane groups)
  const int q    = t & 3;    // k/s quarter
  const int s    = t >> 3;   // 0..63 column (score map, 8-lane groups)
  const int hg   = t & 7;    // h-group of 16

  // ---- register weights: whh rows, interleaved k-map (k = kk*16+q*4+j) ----
  float wr0[32], wr1[32], wr2[32];
#pragma unroll
  for (int kk = 0; kk < 8; ++kk) {
    float4 a = *(const float4*)(whh + g * 128         + kk * 16 + q * 4);
    float4 c = *(const float4*)(whh + (128 + g) * 128 + kk * 16 + q * 4);
    float4 d = *(const float4*)(whh + (256 + g) * 128 + kk * 16 + q * 4);
    wr0[4*kk] = a.x; wr0[4*kk+1] = a.y; wr0[4*kk+2] = a.z; wr0[4*kk+3] = a.w;
    wr1[4*kk] = c.x; wr1[4*kk+1] = c.y; wr1[4*kk+2] = c.z; wr1[4*kk+3] = c.w;
    wr2[4*kk] = d.x; wr2[4*kk+1] = d.y; wr2[4*kk+2] = d.z; wr2[4*kk+3] = d.w;
  }
  float qr[16];
  {
    const float4* pq = (const float4*)(ws + WS_Q + b * 8192 + g * 64 + q * 16);
#pragma unroll
    for (int i = 0; i < 4; ++i) {
      float4 v = pq[i];
      qr[4*i] = v.x; qr[4*i+1] = v.y; qr[4*i+2] = v.z; qr[4*i+3] = v.w;
    }
  }

  // ---- LDS init ----
  {  // W3 row g, granule j stored at (j+g)&31
    const float4* src = (const float4*)(attn_W + g * 384 + 256);
#pragma unroll
    for (int kk = 0; kk < 8; ++kk) {
      int j = q * 8 + kk;
      W3s4[g * 32 + ((j + g) & 31)] = src[j];
    }
  }
  for (int e = t; e < 8192; e += 512) {  // EA/EP transpose + s-rotation
    int h = e >> 6, sE = e & 63;
    int rg = ((h >> 2) + sE) & 31;
    ((float*)EAT4)[sE * 128 + rg * 4 + (h & 3)] = ws[WS_PREA + b * 8192 + e];
    ((float*)EPT4)[sE * 128 + rg * 4 + (h & 3)] = ws[WS_PREP + b * 8192 + e];
  }
  if (t < 128) {
    int h = t;
    int rg = rot8(h >> 1);
    ((float*)uav3)[rg * 4 + (h & 1) * 2 + 1] = 2.0f * attn_v[h];
    ((float*)uav2)[rg * 4 + (h & 1) * 2 + 1] = 2.0f * ptr_v[h];
    stt[h] = statics[b * 128 + h];
    const float* Mm = ws + WS_M;
    const float* Cc = ws + WS_C;
    float cR = Cc[h] + bhh_g[h];
    float cZ = Cc[128 + h] + bhh_g[128 + h];
    gp4[h*3 + 0] = float4{Mm[h*2], Mm[h*2+1], cR, Mm[(128+h)*2]};
    gp4[h*3 + 1] = float4{Mm[(128+h)*2+1], cZ, Mm[(256+h)*2], Mm[(256+h)*2+1]};
    gp4[h*3 + 2] = float4{Cc[256+h], bhh_g[256+h], 0.f, 0.f};
  }
  __syncthreads();

  float hreg = 0.f, ghr = 0.f, ghz = 0.f, ghn = 0.f;
  float d0 = x0[0], d1 = x0[1];

  for (int step = 0; step < 64; ++step) {
    // ---- P1: GRU gates (pointwise; gh carried from prev step) ----
    {
      float4 v0 = gp4[g*3], v1 = gp4[g*3+1], v2 = gp4[g*3+2];
      float r = RCP(1.f + EXP2(-K1 * (v0.x*d0 + v0.y*d1 + v0.z + ghr)));
      float z = RCP(1.f + EXP2(-K1 * (v0.w*d0 + v1.x*d1 + v1.y + ghz)));
      float xn = v1.z*d0 + v1.w*d1 + v2.x + r * (ghn + v2.y);
      float n = 1.f - 2.f * RCP(EXP2(K2 * xn) + 1.f);   // tanh(xn)
      hreg = (1.f - z) * n + z * hreg;
      if (q == 0) hp[(g >> 5) * 36 + (g & 31)] = hreg;
    }
    __syncthreads();                                   // A
    // ---- PB: u3 = W3@h only (gh matvec deferred to C/D windows) ----
    {
      float u3a = 0.f, u3b = 0.f;
#pragma unroll
      for (int kk = 0; kk < 8; ++kk) {
        float4 hv = *(const float4*)&hp[(kk >> 1) * 36 + (kk & 1) * 16 + q * 4];
        float4 wv = W3s4[g * 32 + ((kk * 4 + q + g) & 31)];
        float d2 = wv.x*hv.x + wv.y*hv.y + wv.z*hv.z + wv.w*hv.w;
        if (kk & 1) u3b += d2; else u3a += d2;
      }
      float u3 = sum4(u3a + u3b);
      if (q == 0)
        ((float*)uav3)[rot8(g >> 1) * 4 + (g & 1) * 2] = EXP2(K2 * u3);
    }
    __syncthreads();                                   // B
    float sr = 0.f, sz = 0.f, sn = 0.f;   // gh partials, finalized in PD
    // ---- PC: P3 scores + gh kk=0..3 (independent fill) ----
    {
      float acc0 = 0.f, acc1 = 0.f;
#pragma unroll
      for (int ii = 0; ii < 4; ++ii) {
        float4 ea = EAT4[s * 32 + ((hg * 4 + ii + s) & 31)];
        int p0 = hg * 8 + 2 * ii;
        float4 ua = uav3[(p0 & 56) | ((p0 + hg) & 7)];
        float4 ub = uav3[((p0+1) & 56) | ((p0 + 1 + hg) & 7)];
        acc0 += ua.y * RCP(ea.x * ua.x + 1.f)
              + ua.w * RCP(ea.y * ua.z + 1.f);
        acc1 += ub.y * RCP(ea.z * ub.x + 1.f)
              + ub.w * RCP(ea.w * ub.z + 1.f);
      }
#pragma unroll
      for (int kk = 0; kk < 4; ++kk) {
        float4 hv = *(const float4*)&hp[(kk >> 1) * 36 + (kk & 1) * 16 + q * 4];
        int k = kk * 4;
        sr += wr0[k]*hv.x + wr0[k+1]*hv.y + wr0[k+2]*hv.z + wr0[k+3]*hv.w;
        sz += wr1[k]*hv.x + wr1[k+1]*hv.y + wr1[k+2]*hv.z + wr1[k+3]*hv.w;
        sn += wr2[k]*hv.x + wr2[k+1]*hv.y + wr2[k+2]*hv.z + wr2[k+3]*hv.w;
      }
      float acc = sum8(acc0 + acc1);
      if (hg == 0) a_lds[s] = -acc;
    }
    __syncthreads();                                   // C
    // ---- PD: softmax (no max-shift) + u2 = Q@attns + gh kk=4..7 ----
    {
      float a = a_lds[lane];
      float e = EXP2(K1 * a);          // |a| <~ 20 -> range-safe in f32
      attns[lane] = e;                 // identical writes from all waves
#pragma unroll
      for (int kk = 4; kk < 8; ++kk) { // fill attns write->read latency
        float4 hv = *(const float4*)&hp[(kk >> 1) * 36 + (kk & 1) * 16 + q * 4];
        int k = kk * 4;
        sr += wr0[k]*hv.x + wr0[k+1]*hv.y + wr0[k+2]*hv.z + wr0[k+3]*hv.w;
        sz += wr1[k]*hv.x + wr1[k+1]*hv.y + wr1[k+2]*hv.z + wr1[k+3]*hv.w;
        sn += wr2[k]*hv.x + wr2[k+1]*hv.y + wr2[k+2]*hv.z + wr2[k+3]*hv.w;
      }
      float sum = sum64(e);
      float p = 0.f;
#pragma unroll
      for (int ii = 0; ii < 4; ++ii) {
        float4 av = *(const float4*)&attns[q * 16 + ii * 4];
        p += qr[4*ii]*av.x + qr[4*ii+1]*av.y + qr[4*ii+2]*av.z + qr[4*ii+3]*av.w;
      }
      p *= RCP(sum);
      p = sum4(p);
      if (q == 0)
        ((float*)uav2)[rot8(g >> 1) * 4 + (g & 1) * 2] = EXP2(K2 * p);
      ghr = sum4(sr); ghz = sum4(sz); ghn = sum4(sn);
    }
    __syncthreads();                                   // D
    // ---- PE: ptr logits l'[s] = -sum_h pv2[h]*rcp(EP[h,s]*F2[h]+1) ----
    {
      float acc0 = 0.f, acc1 = 0.f;
#pragma unroll
      for (int ii = 0; ii < 4; ++ii) {
        float4 ep = EPT4[s * 32 + ((hg * 4 + ii + s) & 31)];
        int p0 = hg * 8 + 2 * ii;
        float4 ua = uav2[(p0 & 56) | ((p0 + hg) & 7)];
        float4 ub = uav2[((p0+1) & 56) | ((p0 + 1 + hg) & 7)];
        acc0 += ua.y * RCP(ep.x * ua.x + 1.f)
              + ua.w * RCP(ep.y * ua.z + 1.f);
        acc1 += ub.y * RCP(ep.z * ub.x + 1.f)
              + ub.w * RCP(ep.w * ub.z + 1.f);
      }
      float acc = sum8(acc0 + acc1);
      if (hg == 0) l_lds[s] = -acc;
    }
    __syncthreads();                                   // E
    // ---- P6: argmax via fmax-chain + ballot (first-index tiebreak) ----
    {
      float L = l_lds[lane];
      float v = max64(L);
      unsigned long long mk = __ballot(L == v);   // exact: fmax preserves bits
      int idx = __builtin_ctzll(mk);              // lowest lane = lowest s
      float e2 = EXP2(K1 * (L - v));
      float s3 = sum64(e2);
      if (t == 0) {
        out[b * 64 + step] = (float)idx;                       // tour_idx
        out[8192 + b * 64 + step] = -LN2 * __builtin_amdgcn_logf(s3);  // logp
      }
      d0 = stt[idx];                               // uniform broadcast
      d1 = stt[64 + idx];
    }
    // no barrier: every buffer's next write is >=2 barrier-phases away
  }
}

extern "C" void kernel_launch(void* const* d_in, const int* in_sizes, int n_in,
                              void* d_out, int out_size, void* d_ws, size_t ws_size,
                              hipStream_t stream) {
  const float* statics  = (const float*)d_in[0];
  const float* dynamics = (const float*)d_in[1];
  const float* x0       = (const float*)d_in[2];
  const float* sw       = (const float*)d_in[3];
  const float* sb       = (const float*)d_in[4];
  const float* dw       = (const float*)d_in[5];
  const float* db       = (const float*)d_in[6];
  const float* decw     = (const float*)d_in[7];
  const float* decb     = (const float*)d_in[8];
  const float* wih      = (const float*)d_in[9];
  const float* whh      = (const float*)d_in[10];
  const float* bih      = (const float*)d_in[11];
  const float* bhh      = (const float*)d_in[12];
  const float* attn_v   = (const float*)d_in[13];
  const float* attn_W   = (const float*)d_in[14];
  const float* ptr_v    = (const float*)d_in[15];
  const float* ptr_W    = (const float*)d_in[16];
  float* ws  = (float*)d_ws;
  float* out = (float*)d_out;

  hipLaunchKernelGGL(prep_small, dim3(2), dim3(256), 0, stream,
                     wih, decw, decb, bih, ws);
  hipLaunchKernelGGL(prep_big, dim3(1024), dim3(256), 0, stream,
                     statics, dynamics, sw, sb, dw, db, attn_W, ptr_W, ws);
  hipLaunchKernelGGL(drl4tsp_main, dim3(128), dim3(512), 0, stream,
                     statics, x0, whh, attn_W, bhh, attn_v, ptr_v, ws, out);
}

// Round 10
// 205.389 us; speedup vs baseline: 1.7081x; 1.0590x over previous
//
#include <hip/hip_runtime.h>
#include <math.h>

// Problem dims (fixed): B=128, S=64, H=128, STATIC=DYNAMIC=2
// Outputs: tour_idx [B,S] (as f32), tour_logp [B,S] -> d_out 16384 f32

#define K1  1.44269504088896340736f   // log2(e)
#define K2  2.88539008177792681472f   // 2*log2(e)
#define LN2 0.69314718055994530942f

// ---------------- ws layout (float offsets) ----------------
#define WS_M     0                       // [384][2]   M = wih @ decoder_w
#define WS_C     768                     // [384]      c = wih @ decoder_b + bih
#define WS_PREA  1152                    // [B][128][64] EA = exp2(K2*(W1@sh + W2@dh))
#define WS_PREP  (WS_PREA + 128*8192)    // [B][128][64] EP = exp2(K2*(P1@sh))
#define WS_Q     (WS_PREP + 128*8192)    // [B][128][64] Q  = P2@sh

// ---- DPP cross-lane (VALU-speed) ----
template <int CTRL>
__device__ __forceinline__ float dppf(float x) {
  int xi = __builtin_bit_cast(int, x);
  return __builtin_bit_cast(float,
      __builtin_amdgcn_update_dpp(xi, xi, CTRL, 0xF, 0xF, false));
}
// 0xB1=quad xor1, 0x4E=quad xor2, 0x141=row_half_mirror, 0x128=row_ror:8
__device__ __forceinline__ float sum4(float x) {
  x += dppf<0xB1>(x); x += dppf<0x4E>(x); return x;
}
__device__ __forceinline__ float sum8(float x) {
  x += dppf<0xB1>(x); x += dppf<0x4E>(x); x += dppf<0x141>(x); return x;
}
__device__ __forceinline__ float sum16(float x) {
  x += dppf<0xB1>(x); x += dppf<0x4E>(x); x += dppf<0x141>(x); x += dppf<0x128>(x);
  return x;
}
__device__ __forceinline__ float sum64(float x) {
  x = sum16(x); x += __shfl_xor(x, 16); x += __shfl_xor(x, 32); return x;
}
__device__ __forceinline__ float max64(float x) {
  x = fmaxf(x, dppf<0xB1>(x)); x = fmaxf(x, dppf<0x4E>(x));
  x = fmaxf(x, dppf<0x141>(x)); x = fmaxf(x, dppf<0x128>(x));
  x = fmaxf(x, __shfl_xor(x, 16)); x = fmaxf(x, __shfl_xor(x, 32)); return x;
}
#define RCP(x)  __builtin_amdgcn_rcpf(x)
#define EXP2(x) __builtin_amdgcn_exp2f(x)

// lgkm-only barrier: LDS producer/consumer correctness WITHOUT the vmcnt(0)
// drain __syncthreads() emits (in-flight global loads/stores keep flowing).
// Memory-clobber sandwich pins compiler LDS ordering around s_barrier.
__device__ __forceinline__ void bar_lds() {
  asm volatile("s_waitcnt lgkmcnt(0)" ::: "memory");
  __builtin_amdgcn_s_barrier();
  asm volatile("" ::: "memory");
}

// bijective bank-rotation for pair-granule index p
__device__ __forceinline__ int rot8(int p) {
  return (p & 56) | ((p + (p >> 3)) & 7);
}

// ---------------- tiny precompute: GRU input-path folding ----------------
__global__ __launch_bounds__(256) void prep_small(
    const float* __restrict__ wih, const float* __restrict__ decw,
    const float* __restrict__ decb, const float* __restrict__ bih,
    float* __restrict__ ws) {
  int gid = blockIdx.x * 256 + threadIdx.x;
  if (gid < 384) {
    float m0 = 0.f, m1 = 0.f, cc = 0.f;
    for (int k = 0; k < 128; ++k) {
      float w = wih[gid * 128 + k];
      m0 += w * decw[k * 2 + 0];
      m1 += w * decw[k * 2 + 1];
      cc += w * decb[k];
    }
    ws[WS_M + gid * 2 + 0] = m0;
    ws[WS_M + gid * 2 + 1] = m1;
    ws[WS_C + gid] = cc + bih[gid];
  }
}

// ---------------- big precompute: EA / EP / Q per batch ------------------
__global__ __launch_bounds__(256) void prep_big(
    const float* __restrict__ statics, const float* __restrict__ dynamics,
    const float* __restrict__ sw, const float* __restrict__ sb,
    const float* __restrict__ dw, const float* __restrict__ db,
    const float* __restrict__ attn_W, const float* __restrict__ ptr_W,
    float* __restrict__ ws) {
  __shared__ __align__(16) float sh[128 * 64];
  __shared__ __align__(16) float dh[128 * 64];
  __shared__ float st[128];
  __shared__ float dy[128];
  int b = blockIdx.x >> 3;
  int hq = blockIdx.x & 7;
  int t = threadIdx.x;
  if (t < 128) st[t] = statics[b * 128 + t];
  else         dy[t - 128] = dynamics[b * 128 + (t - 128)];
  __syncthreads();
  for (int e = t; e < 8192; e += 256) {
    int h = e >> 6, s = e & 63;
    sh[e] = sw[h * 2 + 0] * st[s] + sw[h * 2 + 1] * st[64 + s] + sb[h];
    dh[e] = dw[h * 2 + 0] * dy[s] + dw[h * 2 + 1] * dy[64 + s] + db[h];
  }
  __syncthreads();
  int hh = hq * 16 + (t >> 4);
  int s0 = (t & 15) * 4;
  float4 pA = {0, 0, 0, 0}, pP = {0, 0, 0, 0}, qq = {0, 0, 0, 0};
  for (int k = 0; k < 128; ++k) {
    float4 sv = *(const float4*)&sh[k * 64 + s0];
    float4 dv = *(const float4*)&dh[k * 64 + s0];
    float w1 = attn_W[hh * 384 + k];
    float w2 = attn_W[hh * 384 + 128 + k];
    float p1 = ptr_W[hh * 256 + k];
    float p2 = ptr_W[hh * 256 + 128 + k];
    pA.x += w1 * sv.x + w2 * dv.x;  pA.y += w1 * sv.y + w2 * dv.y;
    pA.z += w1 * sv.z + w2 * dv.z;  pA.w += w1 * sv.w + w2 * dv.w;
    pP.x += p1 * sv.x;  pP.y += p1 * sv.y;  pP.z += p1 * sv.z;  pP.w += p1 * sv.w;
    qq.x += p2 * sv.x;  qq.y += p2 * sv.y;  qq.z += p2 * sv.z;  qq.w += p2 * sv.w;
  }
  // store exp-transformed score bases (shared-exp tanh trick)
  float4 eA, eP;
  eA.x = exp2f(K2 * pA.x); eA.y = exp2f(K2 * pA.y);
  eA.z = exp2f(K2 * pA.z); eA.w = exp2f(K2 * pA.w);
  eP.x = exp2f(K2 * pP.x); eP.y = exp2f(K2 * pP.y);
  eP.z = exp2f(K2 * pP.z); eP.w = exp2f(K2 * pP.w);
  int o = b * 8192 + hh * 64 + s0;
  *(float4*)&ws[WS_PREA + o] = eA;
  *(float4*)&ws[WS_PREP + o] = eP;
  *(float4*)&ws[WS_Q + o]    = qq;
}

// ---------------- main recurrence: 1 block/batch, 512 thr, 64 steps -----
// Round-10 deltas: lgkm-only barriers (no vmcnt drain), outputs buffered in
// LDS (no in-loop global stores), EPT reads prefetched under PD's softmax
// chain, paired rcps in score phases (16 -> 8 quarter-rate ops).
__global__ __launch_bounds__(512)
__attribute__((amdgpu_waves_per_eu(2)))
void drl4tsp_main(
    const float* __restrict__ statics, const float* __restrict__ x0,
    const float* __restrict__ whh, const float* __restrict__ attn_W,
    const float* __restrict__ bhh_g, const float* __restrict__ attn_v,
    const float* __restrict__ ptr_v, const float* __restrict__ ws,
    float* __restrict__ out) {
  __shared__ float4 W3s4[128 * 32];   // 64KB [g][(j+g)&31]
  __shared__ float4 EAT4[64 * 32];    // 32KB [s][(gi+s)&31] (transposed)
  __shared__ float4 EPT4[64 * 32];    // 32KB
  __shared__ float4 uav3[64];         // {u3f,av2} pairs @ rot8(p)
  __shared__ float4 uav2[64];         // {u2f,pv2} pairs @ rot8(p)
  __shared__ float4 gp4[128 * 3];     // 6KB gate params
  __shared__ __align__(16) float hp[144];     // h padded: [k>>5]*36 + (k&31)
  __shared__ __align__(16) float attns[64];   // shared e-buffer
  __shared__ float a_lds[64];
  __shared__ float l_lds[64];
  __shared__ float stt[128];
  __shared__ float outbuf[128];       // [0..63] idx, [64..127] logp

  const int b    = blockIdx.x;
  const int t    = threadIdx.x;
  const int lane = t & 63;
  const int g    = t >> 2;   // 0..127 row (matvec map, 4-lane groups)
  const int q    = t & 3;    // k/s quarter
  const int s    = t >> 3;   // 0..63 column (score map, 8-lane groups)
  const int hg   = t & 7;    // h-group of 16

  // ---- register weights: whh rows, interleaved k-map (k = kk*16+q*4+j) ----
  float wr0[32], wr1[32], wr2[32];
#pragma unroll
  for (int kk = 0; kk < 8; ++kk) {
    float4 a = *(const float4*)(whh + g * 128         + kk * 16 + q * 4);
    float4 c = *(const float4*)(whh + (128 + g) * 128 + kk * 16 + q * 4);
    float4 d = *(const float4*)(whh + (256 + g) * 128 + kk * 16 + q * 4);
    wr0[4*kk] = a.x; wr0[4*kk+1] = a.y; wr0[4*kk+2] = a.z; wr0[4*kk+3] = a.w;
    wr1[4*kk] = c.x; wr1[4*kk+1] = c.y; wr1[4*kk+2] = c.z; wr1[4*kk+3] = c.w;
    wr2[4*kk] = d.x; wr2[4*kk+1] = d.y; wr2[4*kk+2] = d.z; wr2[4*kk+3] = d.w;
  }
  float qr[16];
  {
    const float4* pq = (const float4*)(ws + WS_Q + b * 8192 + g * 64 + q * 16);
#pragma unroll
    for (int i = 0; i < 4; ++i) {
      float4 v = pq[i];
      qr[4*i] = v.x; qr[4*i+1] = v.y; qr[4*i+2] = v.z; qr[4*i+3] = v.w;
    }
  }

  // ---- LDS init ----
  {  // W3 row g, granule j stored at (j+g)&31
    const float4* src = (const float4*)(attn_W + g * 384 + 256);
#pragma unroll
    for (int kk = 0; kk < 8; ++kk) {
      int j = q * 8 + kk;
      W3s4[g * 32 + ((j + g) & 31)] = src[j];
    }
  }
  for (int e = t; e < 8192; e += 512) {  // EA/EP transpose + s-rotation
    int h = e >> 6, sE = e & 63;
    int rg = ((h >> 2) + sE) & 31;
    ((float*)EAT4)[sE * 128 + rg * 4 + (h & 3)] = ws[WS_PREA + b * 8192 + e];
    ((float*)EPT4)[sE * 128 + rg * 4 + (h & 3)] = ws[WS_PREP + b * 8192 + e];
  }
  if (t < 128) {
    int h = t;
    int rg = rot8(h >> 1);
    ((float*)uav3)[rg * 4 + (h & 1) * 2 + 1] = 2.0f * attn_v[h];
    ((float*)uav2)[rg * 4 + (h & 1) * 2 + 1] = 2.0f * ptr_v[h];
    stt[h] = statics[b * 128 + h];
    const float* Mm = ws + WS_M;
    const float* Cc = ws + WS_C;
    float cR = Cc[h] + bhh_g[h];
    float cZ = Cc[128 + h] + bhh_g[128 + h];
    gp4[h*3 + 0] = float4{Mm[h*2], Mm[h*2+1], cR, Mm[(128+h)*2]};
    gp4[h*3 + 1] = float4{Mm[(128+h)*2+1], cZ, Mm[(256+h)*2], Mm[(256+h)*2+1]};
    gp4[h*3 + 2] = float4{Cc[256+h], bhh_g[256+h], 0.f, 0.f};
  }
  __syncthreads();

  float hreg = 0.f, ghr = 0.f, ghz = 0.f, ghn = 0.f;
  float d0 = x0[0], d1 = x0[1];

  for (int step = 0; step < 64; ++step) {
    // ---- P1: GRU gates (pointwise; gh carried from prev step) ----
    {
      float4 v0 = gp4[g*3], v1 = gp4[g*3+1], v2 = gp4[g*3+2];
      float r = RCP(1.f + EXP2(-K1 * (v0.x*d0 + v0.y*d1 + v0.z + ghr)));
      float z = RCP(1.f + EXP2(-K1 * (v0.w*d0 + v1.x*d1 + v1.y + ghz)));
      float xn = v1.z*d0 + v1.w*d1 + v2.x + r * (ghn + v2.y);
      float n = 1.f - 2.f * RCP(EXP2(K2 * xn) + 1.f);   // tanh(xn)
      hreg = (1.f - z) * n + z * hreg;
      if (q == 0) hp[(g >> 5) * 36 + (g & 31)] = hreg;
    }
    bar_lds();                                         // A
    // ---- PB: u3 = W3@h only (gh matvec deferred to C/D windows) ----
    {
      float u3a = 0.f, u3b = 0.f;
#pragma unroll
      for (int kk = 0; kk < 8; ++kk) {
        float4 hv = *(const float4*)&hp[(kk >> 1) * 36 + (kk & 1) * 16 + q * 4];
        float4 wv = W3s4[g * 32 + ((kk * 4 + q + g) & 31)];
        float d2 = wv.x*hv.x + wv.y*hv.y + wv.z*hv.z + wv.w*hv.w;
        if (kk & 1) u3b += d2; else u3a += d2;
      }
      float u3 = sum4(u3a + u3b);
      if (q == 0)
        ((float*)uav3)[rot8(g >> 1) * 4 + (g & 1) * 2] = EXP2(K2 * u3);
    }
    bar_lds();                                         // B
    float sr = 0.f, sz = 0.f, sn = 0.f;   // gh partials, finalized in PD
    // ---- PC: attn scores (paired rcp) + gh kk=0..3 (independent fill) --
    {
      float acc0 = 0.f, acc1 = 0.f;
#pragma unroll
      for (int ii = 0; ii < 4; ++ii) {
        float4 ea = EAT4[s * 32 + ((hg * 4 + ii + s) & 31)];
        int p0 = hg * 8 + 2 * ii;
        float4 ua = uav3[(p0 & 56) | ((p0 + hg) & 7)];
        float4 ub = uav3[((p0+1) & 56) | ((p0 + 1 + hg) & 7)];
        float x1 = ea.x * ua.x + 1.f, y1 = ea.y * ua.z + 1.f;
        acc0 += (ua.y * y1 + ua.w * x1) * RCP(x1 * y1);
        float x2 = ea.z * ub.x + 1.f, y2 = ea.w * ub.z + 1.f;
        acc1 += (ub.y * y2 + ub.w * x2) * RCP(x2 * y2);
      }
#pragma unroll
      for (int kk = 0; kk < 4; ++kk) {
        float4 hv = *(const float4*)&hp[(kk >> 1) * 36 + (kk & 1) * 16 + q * 4];
        int k = kk * 4;
        sr += wr0[k]*hv.x + wr0[k+1]*hv.y + wr0[k+2]*hv.z + wr0[k+3]*hv.w;
        sz += wr1[k]*hv.x + wr1[k+1]*hv.y + wr1[k+2]*hv.z + wr1[k+3]*hv.w;
        sn += wr2[k]*hv.x + wr2[k+1]*hv.y + wr2[k+2]*hv.z + wr2[k+3]*hv.w;
      }
      float acc = sum8(acc0 + acc1);
      if (hg == 0) a_lds[s] = -acc;
    }
    bar_lds();                                         // C
    // ---- PD: softmax (no max-shift) + u2 = Q@attns + gh kk=4..7
    //          + EPT prefetch for PE (issued under the softmax chain) ----
    float4 ep0, ep1, ep2, ep3;
    {
      float a = a_lds[lane];
      ep0 = EPT4[s * 32 + ((hg * 4 + 0 + s) & 31)];   // prefetch (indep.)
      ep1 = EPT4[s * 32 + ((hg * 4 + 1 + s) & 31)];
      ep2 = EPT4[s * 32 + ((hg * 4 + 2 + s) & 31)];
      ep3 = EPT4[s * 32 + ((hg * 4 + 3 + s) & 31)];
      float e = EXP2(K1 * a);          // |a| <~ 20 -> range-safe in f32
      attns[lane] = e;                 // identical writes from all waves
#pragma unroll
      for (int kk = 4; kk < 8; ++kk) { // fill attns write->read latency
        float4 hv = *(const float4*)&hp[(kk >> 1) * 36 + (kk & 1) * 16 + q * 4];
        int k = kk * 4;
        sr += wr0[k]*hv.x + wr0[k+1]*hv.y + wr0[k+2]*hv.z + wr0[k+3]*hv.w;
        sz += wr1[k]*hv.x + wr1[k+1]*hv.y + wr1[k+2]*hv.z + wr1[k+3]*hv.w;
        sn += wr2[k]*hv.x + wr2[k+1]*hv.y + wr2[k+2]*hv.z + wr2[k+3]*hv.w;
      }
      float sum = sum64(e);
      float p = 0.f;
#pragma unroll
      for (int ii = 0; ii < 4; ++ii) {
        float4 av = *(const float4*)&attns[q * 16 + ii * 4];
        p += qr[4*ii]*av.x + qr[4*ii+1]*av.y + qr[4*ii+2]*av.z + qr[4*ii+3]*av.w;
      }
      p *= RCP(sum);
      p = sum4(p);
      if (q == 0)
        ((float*)uav2)[rot8(g >> 1) * 4 + (g & 1) * 2] = EXP2(K2 * p);
      ghr = sum4(sr); ghz = sum4(sz); ghn = sum4(sn);
    }
    bar_lds();                                         // D
    // ---- PE: ptr logits (paired rcp, EPT prefetched) ----
    {
      float acc0 = 0.f, acc1 = 0.f;
#pragma unroll
      for (int ii = 0; ii < 4; ++ii) {
        float4 ep = (ii == 0) ? ep0 : (ii == 1) ? ep1 : (ii == 2) ? ep2 : ep3;
        int p0 = hg * 8 + 2 * ii;
        float4 ua = uav2[(p0 & 56) | ((p0 + hg) & 7)];
        float4 ub = uav2[((p0+1) & 56) | ((p0 + 1 + hg) & 7)];
        float x1 = ep.x * ua.x + 1.f, y1 = ep.y * ua.z + 1.f;
        acc0 += (ua.y * y1 + ua.w * x1) * RCP(x1 * y1);
        float x2 = ep.z * ub.x + 1.f, y2 = ep.w * ub.z + 1.f;
        acc1 += (ub.y * y2 + ub.w * x2) * RCP(x2 * y2);
      }
      float acc = sum8(acc0 + acc1);
      if (hg == 0) l_lds[s] = -acc;
    }
    bar_lds();                                         // E
    // ---- P6: argmax via fmax-chain + ballot (first-index tiebreak) ----
    {
      float L = l_lds[lane];
      float v = max64(L);
      unsigned long long mk = __ballot(L == v);   // exact: fmax preserves bits
      int idx = __builtin_ctzll(mk);              // lowest lane = lowest s
      float e2 = EXP2(K1 * (L - v));
      float s3 = sum64(e2);
      if (t == 0) {
        outbuf[step] = (float)idx;                             // tour_idx
        outbuf[64 + step] = -LN2 * __builtin_amdgcn_logf(s3);  // logp
      }
      d0 = stt[idx];                               // uniform broadcast
      d1 = stt[64 + idx];
    }
    // no barrier: every buffer's next write is >=2 barrier-phases away
  }
  bar_lds();
  if (t < 64)        out[b * 64 + t]         = outbuf[t];
  else if (t < 128)  out[8192 + b * 64 + (t - 64)] = outbuf[t];
}

extern "C" void kernel_launch(void* const* d_in, const int* in_sizes, int n_in,
                              void* d_out, int out_size, void* d_ws, size_t ws_size,
                              hipStream_t stream) {
  const float* statics  = (const float*)d_in[0];
  const float* dynamics = (const float*)d_in[1];
  const float* x0       = (const float*)d_in[2];
  const float* sw       = (const float*)d_in[3];
  const float* sb       = (const float*)d_in[4];
  const float* dw       = (const float*)d_in[5];
  const float* db       = (const float*)d_in[6];
  const float* decw     = (const float*)d_in[7];
  const float* decb     = (const float*)d_in[8];
  const float* wih      = (const float*)d_in[9];
  const float* whh      = (const float*)d_in[10];
  const float* bih      = (const float*)d_in[11];
  const float* bhh      = (const float*)d_in[12];
  const float* attn_v   = (const float*)d_in[13];
  const float* attn_W   = (const float*)d_in[14];
  const float* ptr_v    = (const float*)d_in[15];
  const float* ptr_W    = (const float*)d_in[16];
  float* ws  = (float*)d_ws;
  float* out = (float*)d_out;

  hipLaunchKernelGGL(prep_small, dim3(2), dim3(256), 0, stream,
                     wih, decw, decb, bih, ws);
  hipLaunchKernelGGL(prep_big, dim3(1024), dim3(256), 0, stream,
                     statics, dynamics, sw, sb, dw, db, attn_W, ptr_W, ws);
  hipLaunchKernelGGL(drl4tsp_main, dim3(128), dim3(512), 0, stream,
                     statics, x0, whh, attn_W, bhh, attn_v, ptr_v, ws, out);
}

// Round 11
// 202.826 us; speedup vs baseline: 1.7297x; 1.0126x over previous
//
#include <hip/hip_runtime.h>
#include <math.h>

// Problem dims (fixed): B=128, S=64, H=128, STATIC=DYNAMIC=2
// Outputs: tour_idx [B,S] (as f32), tour_logp [B,S] -> d_out 16384 f32

#define K1  1.44269504088896340736f   // log2(e)
#define K2  2.88539008177792681472f   // 2*log2(e)
#define LN2 0.69314718055994530942f

// ---------------- ws layout (float offsets) ----------------
#define WS_M     0                       // [384][2]   M = wih @ decoder_w
#define WS_C     768                     // [384]      c = wih @ decoder_b + bih
#define WS_PREA  1152                    // [B][128][64] EA = exp2(K2*(W1@sh + W2@dh))
#define WS_PREP  (WS_PREA + 128*8192)    // [B][128][64] EP = exp2(K2*(P1@sh))
#define WS_Q     (WS_PREP + 128*8192)    // [B][128][64] Q  = P2@sh

// ---- DPP cross-lane (VALU-speed) ----
template <int CTRL>
__device__ __forceinline__ float dppk(float x) {  // bound_ctrl=0: keep self
  int xi = __builtin_bit_cast(int, x);
  return __builtin_bit_cast(float,
      __builtin_amdgcn_update_dpp(xi, xi, CTRL, 0xF, 0xF, false));
}
template <int CTRL>
__device__ __forceinline__ float dppz(float x) {  // bound_ctrl=1: zero-fill
  int xi = __builtin_bit_cast(int, x);
  return __builtin_bit_cast(float,
      __builtin_amdgcn_update_dpp(0, xi, CTRL, 0xF, 0xF, true));
}
__device__ __forceinline__ float bcastf(float x, int lane) {
  return __builtin_bit_cast(float,
      __builtin_amdgcn_readlane(__builtin_bit_cast(int, x), lane));
}
// 0xB1=quad xor1, 0x4E=quad xor2, 0x141=row_half_mirror
__device__ __forceinline__ float sum4(float x) {
  x += dppk<0xB1>(x); x += dppk<0x4E>(x); return x;
}
__device__ __forceinline__ float sum8(float x) {
  x += dppk<0xB1>(x); x += dppk<0x4E>(x); x += dppk<0x141>(x); return x;
}
// wave64 reductions, prefix style: row_shr:1/2/4/8 + row_bcast:15/31, then
// readlane(63) -> uniform SGPR value. Zero LDS crossings (all VALU DPP).
__device__ __forceinline__ float wsum64(float x) {
  x += dppz<0x111>(x); x += dppz<0x112>(x); x += dppz<0x114>(x);
  x += dppz<0x118>(x); x += dppz<0x142>(x); x += dppz<0x143>(x);
  return bcastf(x, 63);
}
__device__ __forceinline__ float wmax64(float x) {
  x = fmaxf(x, dppk<0x111>(x)); x = fmaxf(x, dppk<0x112>(x));
  x = fmaxf(x, dppk<0x114>(x)); x = fmaxf(x, dppk<0x118>(x));
  x = fmaxf(x, dppk<0x142>(x)); x = fmaxf(x, dppk<0x143>(x));
  return bcastf(x, 63);
}
#define RCP(x)  __builtin_amdgcn_rcpf(x)
#define EXP2(x) __builtin_amdgcn_exp2f(x)

// lgkm-only barrier: LDS producer/consumer correctness WITHOUT the vmcnt(0)
// drain __syncthreads() emits (in-flight global loads/stores keep flowing).
__device__ __forceinline__ void bar_lds() {
  asm volatile("s_waitcnt lgkmcnt(0)" ::: "memory");
  __builtin_amdgcn_s_barrier();
  asm volatile("" ::: "memory");
}

// bijective bank-rotation for pair-granule index p
__device__ __forceinline__ int rot8(int p) {
  return (p & 56) | ((p + (p >> 3)) & 7);
}

// ---------------- tiny precompute: GRU input-path folding ----------------
__global__ __launch_bounds__(256) void prep_small(
    const float* __restrict__ wih, const float* __restrict__ decw,
    const float* __restrict__ decb, const float* __restrict__ bih,
    float* __restrict__ ws) {
  int gid = blockIdx.x * 256 + threadIdx.x;
  if (gid < 384) {
    float m0 = 0.f, m1 = 0.f, cc = 0.f;
    for (int k = 0; k < 128; ++k) {
      float w = wih[gid * 128 + k];
      m0 += w * decw[k * 2 + 0];
      m1 += w * decw[k * 2 + 1];
      cc += w * decb[k];
    }
    ws[WS_M + gid * 2 + 0] = m0;
    ws[WS_M + gid * 2 + 1] = m1;
    ws[WS_C + gid] = cc + bih[gid];
  }
}

// ---------------- big precompute: EA / EP / Q per batch ------------------
__global__ __launch_bounds__(256) void prep_big(
    const float* __restrict__ statics, const float* __restrict__ dynamics,
    const float* __restrict__ sw, const float* __restrict__ sb,
    const float* __restrict__ dw, const float* __restrict__ db,
    const float* __restrict__ attn_W, const float* __restrict__ ptr_W,
    float* __restrict__ ws) {
  __shared__ __align__(16) float sh[128 * 64];
  __shared__ __align__(16) float dh[128 * 64];
  __shared__ float st[128];
  __shared__ float dy[128];
  int b = blockIdx.x >> 3;
  int hq = blockIdx.x & 7;
  int t = threadIdx.x;
  if (t < 128) st[t] = statics[b * 128 + t];
  else         dy[t - 128] = dynamics[b * 128 + (t - 128)];
  __syncthreads();
  for (int e = t; e < 8192; e += 256) {
    int h = e >> 6, s = e & 63;
    sh[e] = sw[h * 2 + 0] * st[s] + sw[h * 2 + 1] * st[64 + s] + sb[h];
    dh[e] = dw[h * 2 + 0] * dy[s] + dw[h * 2 + 1] * dy[64 + s] + db[h];
  }
  __syncthreads();
  int hh = hq * 16 + (t >> 4);
  int s0 = (t & 15) * 4;
  float4 pA = {0, 0, 0, 0}, pP = {0, 0, 0, 0}, qq = {0, 0, 0, 0};
  for (int k = 0; k < 128; ++k) {
    float4 sv = *(const float4*)&sh[k * 64 + s0];
    float4 dv = *(const float4*)&dh[k * 64 + s0];
    float w1 = attn_W[hh * 384 + k];
    float w2 = attn_W[hh * 384 + 128 + k];
    float p1 = ptr_W[hh * 256 + k];
    float p2 = ptr_W[hh * 256 + 128 + k];
    pA.x += w1 * sv.x + w2 * dv.x;  pA.y += w1 * sv.y + w2 * dv.y;
    pA.z += w1 * sv.z + w2 * dv.z;  pA.w += w1 * sv.w + w2 * dv.w;
    pP.x += p1 * sv.x;  pP.y += p1 * sv.y;  pP.z += p1 * sv.z;  pP.w += p1 * sv.w;
    qq.x += p2 * sv.x;  qq.y += p2 * sv.y;  qq.z += p2 * sv.z;  qq.w += p2 * sv.w;
  }
  // store exp-transformed score bases (shared-exp tanh trick)
  float4 eA, eP;
  eA.x = exp2f(K2 * pA.x); eA.y = exp2f(K2 * pA.y);
  eA.z = exp2f(K2 * pA.z); eA.w = exp2f(K2 * pA.w);
  eP.x = exp2f(K2 * pP.x); eP.y = exp2f(K2 * pP.y);
  eP.z = exp2f(K2 * pP.z); eP.w = exp2f(K2 * pP.w);
  int o = b * 8192 + hh * 64 + s0;
  *(float4*)&ws[WS_PREA + o] = eA;
  *(float4*)&ws[WS_PREP + o] = eP;
  *(float4*)&ws[WS_Q + o]    = qq;
}

// ---------------- main recurrence: 1 block/batch, 512 thr, 64 steps -----
// Round-11 deltas: all-DPP prefix reductions (row_shr + row_bcast + readlane,
// no ds_swizzle crossings); logp computation deferred out of the loop via an
// Lhist archive (P6 = read L -> DPP max -> ballot -> feedback only).
__global__ __launch_bounds__(512)
__attribute__((amdgpu_waves_per_eu(2)))
void drl4tsp_main(
    const float* __restrict__ statics, const float* __restrict__ x0,
    const float* __restrict__ whh, const float* __restrict__ attn_W,
    const float* __restrict__ bhh_g, const float* __restrict__ attn_v,
    const float* __restrict__ ptr_v, const float* __restrict__ ws,
    float* __restrict__ out) {
  __shared__ float4 W3s4[128 * 32];   // 64KB [g][(j+g)&31]
  __shared__ float4 EAT4[64 * 32];    // 32KB [s][(gi+s)&31] (transposed)
  __shared__ float4 EPT4[64 * 32];    // 32KB
  __shared__ float4 uav3[64];         // {u3f,av2} pairs @ rot8(p)
  __shared__ float4 uav2[64];         // {u2f,pv2} pairs @ rot8(p)
  __shared__ float4 gp4[128 * 3];     // 6KB gate params
  __shared__ __align__(16) float hp[144];     // h padded: [k>>5]*36 + (k&31)
  __shared__ __align__(16) float attns[64];   // shared e-buffer
  __shared__ float a_lds[64];
  __shared__ float l_lds[64];
  __shared__ float stt[128];
  __shared__ float outbuf[64];        // per-step argmax idx
  __shared__ float Lhist[4096];       // 16KB: logits archive [step][s]

  const int b    = blockIdx.x;
  const int t    = threadIdx.x;
  const int lane = t & 63;
  const int g    = t >> 2;   // 0..127 row (matvec map, 4-lane groups)
  const int q    = t & 3;    // k/s quarter
  const int s    = t >> 3;   // 0..63 column (score map, 8-lane groups)
  const int hg   = t & 7;    // h-group of 16

  // ---- register weights: whh rows, interleaved k-map (k = kk*16+q*4+j) ----
  float wr0[32], wr1[32], wr2[32];
#pragma unroll
  for (int kk = 0; kk < 8; ++kk) {
    float4 a = *(const float4*)(whh + g * 128         + kk * 16 + q * 4);
    float4 c = *(const float4*)(whh + (128 + g) * 128 + kk * 16 + q * 4);
    float4 d = *(const float4*)(whh + (256 + g) * 128 + kk * 16 + q * 4);
    wr0[4*kk] = a.x; wr0[4*kk+1] = a.y; wr0[4*kk+2] = a.z; wr0[4*kk+3] = a.w;
    wr1[4*kk] = c.x; wr1[4*kk+1] = c.y; wr1[4*kk+2] = c.z; wr1[4*kk+3] = c.w;
    wr2[4*kk] = d.x; wr2[4*kk+1] = d.y; wr2[4*kk+2] = d.z; wr2[4*kk+3] = d.w;
  }
  float qr[16];
  {
    const float4* pq = (const float4*)(ws + WS_Q + b * 8192 + g * 64 + q * 16);
#pragma unroll
    for (int i = 0; i < 4; ++i) {
      float4 v = pq[i];
      qr[4*i] = v.x; qr[4*i+1] = v.y; qr[4*i+2] = v.z; qr[4*i+3] = v.w;
    }
  }

  // ---- LDS init ----
  {  // W3 row g, granule j stored at (j+g)&31
    const float4* src = (const float4*)(attn_W + g * 384 + 256);
#pragma unroll
    for (int kk = 0; kk < 8; ++kk) {
      int j = q * 8 + kk;
      W3s4[g * 32 + ((j + g) & 31)] = src[j];
    }
  }
  for (int e = t; e < 8192; e += 512) {  // EA/EP transpose + s-rotation
    int h = e >> 6, sE = e & 63;
    int rg = ((h >> 2) + sE) & 31;
    ((float*)EAT4)[sE * 128 + rg * 4 + (h & 3)] = ws[WS_PREA + b * 8192 + e];
    ((float*)EPT4)[sE * 128 + rg * 4 + (h & 3)] = ws[WS_PREP + b * 8192 + e];
  }
  if (t < 128) {
    int h = t;
    int rg = rot8(h >> 1);
    ((float*)uav3)[rg * 4 + (h & 1) * 2 + 1] = 2.0f * attn_v[h];
    ((float*)uav2)[rg * 4 + (h & 1) * 2 + 1] = 2.0f * ptr_v[h];
    stt[h] = statics[b * 128 + h];
    const float* Mm = ws + WS_M;
    const float* Cc = ws + WS_C;
    float cR = Cc[h] + bhh_g[h];
    float cZ = Cc[128 + h] + bhh_g[128 + h];
    gp4[h*3 + 0] = float4{Mm[h*2], Mm[h*2+1], cR, Mm[(128+h)*2]};
    gp4[h*3 + 1] = float4{Mm[(128+h)*2+1], cZ, Mm[(256+h)*2], Mm[(256+h)*2+1]};
    gp4[h*3 + 2] = float4{Cc[256+h], bhh_g[256+h], 0.f, 0.f};
  }
  __syncthreads();

  float hreg = 0.f, ghr = 0.f, ghz = 0.f, ghn = 0.f;
  float d0 = x0[0], d1 = x0[1];

  for (int step = 0; step < 64; ++step) {
    // ---- P1: GRU gates (pointwise; gh carried from prev step) ----
    {
      float4 v0 = gp4[g*3], v1 = gp4[g*3+1], v2 = gp4[g*3+2];
      float r = RCP(1.f + EXP2(-K1 * (v0.x*d0 + v0.y*d1 + v0.z + ghr)));
      float z = RCP(1.f + EXP2(-K1 * (v0.w*d0 + v1.x*d1 + v1.y + ghz)));
      float xn = v1.z*d0 + v1.w*d1 + v2.x + r * (ghn + v2.y);
      float n = 1.f - 2.f * RCP(EXP2(K2 * xn) + 1.f);   // tanh(xn)
      hreg = (1.f - z) * n + z * hreg;
      if (q == 0) hp[(g >> 5) * 36 + (g & 31)] = hreg;
    }
    bar_lds();                                         // A
    // ---- PB: u3 = W3@h only (gh matvec deferred to C/D windows) ----
    {
      float u3a = 0.f, u3b = 0.f;
#pragma unroll
      for (int kk = 0; kk < 8; ++kk) {
        float4 hv = *(const float4*)&hp[(kk >> 1) * 36 + (kk & 1) * 16 + q * 4];
        float4 wv = W3s4[g * 32 + ((kk * 4 + q + g) & 31)];
        float d2 = wv.x*hv.x + wv.y*hv.y + wv.z*hv.z + wv.w*hv.w;
        if (kk & 1) u3b += d2; else u3a += d2;
      }
      float u3 = sum4(u3a + u3b);
      if (q == 0)
        ((float*)uav3)[rot8(g >> 1) * 4 + (g & 1) * 2] = EXP2(K2 * u3);
    }
    bar_lds();                                         // B
    float sr = 0.f, sz = 0.f, sn = 0.f;   // gh partials, finalized in PD
    // ---- PC: attn scores (paired rcp) + gh kk=0..3 (independent fill) --
    {
      float acc0 = 0.f, acc1 = 0.f;
#pragma unroll
      for (int ii = 0; ii < 4; ++ii) {
        float4 ea = EAT4[s * 32 + ((hg * 4 + ii + s) & 31)];
        int p0 = hg * 8 + 2 * ii;
        float4 ua = uav3[(p0 & 56) | ((p0 + hg) & 7)];
        float4 ub = uav3[((p0+1) & 56) | ((p0 + 1 + hg) & 7)];
        float x1 = ea.x * ua.x + 1.f, y1 = ea.y * ua.z + 1.f;
        acc0 += (ua.y * y1 + ua.w * x1) * RCP(x1 * y1);
        float x2 = ea.z * ub.x + 1.f, y2 = ea.w * ub.z + 1.f;
        acc1 += (ub.y * y2 + ub.w * x2) * RCP(x2 * y2);
      }
#pragma unroll
      for (int kk = 0; kk < 4; ++kk) {
        float4 hv = *(const float4*)&hp[(kk >> 1) * 36 + (kk & 1) * 16 + q * 4];
        int k = kk * 4;
        sr += wr0[k]*hv.x + wr0[k+1]*hv.y + wr0[k+2]*hv.z + wr0[k+3]*hv.w;
        sz += wr1[k]*hv.x + wr1[k+1]*hv.y + wr1[k+2]*hv.z + wr1[k+3]*hv.w;
        sn += wr2[k]*hv.x + wr2[k+1]*hv.y + wr2[k+2]*hv.z + wr2[k+3]*hv.w;
      }
      float acc = sum8(acc0 + acc1);
      if (hg == 0) a_lds[s] = -acc;
    }
    bar_lds();                                         // C
    // ---- PD: softmax (no max-shift) + u2 = Q@attns + gh kk=4..7
    //          + EPT prefetch for PE (issued under the softmax chain) ----
    float4 ep0, ep1, ep2, ep3;
    {
      float a = a_lds[lane];
      ep0 = EPT4[s * 32 + ((hg * 4 + 0 + s) & 31)];   // prefetch (indep.)
      ep1 = EPT4[s * 32 + ((hg * 4 + 1 + s) & 31)];
      ep2 = EPT4[s * 32 + ((hg * 4 + 2 + s) & 31)];
      ep3 = EPT4[s * 32 + ((hg * 4 + 3 + s) & 31)];
      float e = EXP2(K1 * a);          // |a| <~ 20 -> range-safe in f32
      attns[lane] = e;                 // identical writes from all waves
#pragma unroll
      for (int kk = 4; kk < 8; ++kk) { // fill attns write->read latency
        float4 hv = *(const float4*)&hp[(kk >> 1) * 36 + (kk & 1) * 16 + q * 4];
        int k = kk * 4;
        sr += wr0[k]*hv.x + wr0[k+1]*hv.y + wr0[k+2]*hv.z + wr0[k+3]*hv.w;
        sz += wr1[k]*hv.x + wr1[k+1]*hv.y + wr1[k+2]*hv.z + wr1[k+3]*hv.w;
        sn += wr2[k]*hv.x + wr2[k+1]*hv.y + wr2[k+2]*hv.z + wr2[k+3]*hv.w;
      }
      float sum = wsum64(e);           // all-DPP prefix + readlane (uniform)
      float p = 0.f;
#pragma unroll
      for (int ii = 0; ii < 4; ++ii) {
        float4 av = *(const float4*)&attns[q * 16 + ii * 4];
        p += qr[4*ii]*av.x + qr[4*ii+1]*av.y + qr[4*ii+2]*av.z + qr[4*ii+3]*av.w;
      }
      p *= RCP(sum);
      p = sum4(p);
      if (q == 0)
        ((float*)uav2)[rot8(g >> 1) * 4 + (g & 1) * 2] = EXP2(K2 * p);
      ghr = sum4(sr); ghz = sum4(sz); ghn = sum4(sn);
    }
    bar_lds();                                         // D
    // ---- PE: ptr logits (paired rcp, EPT prefetched) ----
    {
      float acc0 = 0.f, acc1 = 0.f;
#pragma unroll
      for (int ii = 0; ii < 4; ++ii) {
        float4 ep = (ii == 0) ? ep0 : (ii == 1) ? ep1 : (ii == 2) ? ep2 : ep3;
        int p0 = hg * 8 + 2 * ii;
        float4 ua = uav2[(p0 & 56) | ((p0 + hg) & 7)];
        float4 ub = uav2[((p0+1) & 56) | ((p0 + 1 + hg) & 7)];
        float x1 = ep.x * ua.x + 1.f, y1 = ep.y * ua.z + 1.f;
        acc0 += (ua.y * y1 + ua.w * x1) * RCP(x1 * y1);
        float x2 = ep.z * ub.x + 1.f, y2 = ep.w * ub.z + 1.f;
        acc1 += (ub.y * y2 + ub.w * x2) * RCP(x2 * y2);
      }
      float acc = sum8(acc0 + acc1);
      if (hg == 0) l_lds[s] = -acc;
    }
    bar_lds();                                         // E
    // ---- P6: argmax only (logp deferred); DPP max + ballot/ctz ----
    {
      float L = l_lds[lane];
      float v = wmax64(L);                        // uniform via readlane
      unsigned long long mk = __ballot(L == v);   // exact bit-compare
      int idx = __builtin_ctzll(mk);              // lowest lane = lowest s
      if (t < 64) Lhist[step * 64 + t] = L;       // archive for logp pass
      if (t == 0) outbuf[step] = (float)idx;
      d0 = stt[idx];                              // uniform broadcast
      d1 = stt[64 + idx];
    }
    // no barrier: every buffer's next write is >=2 barrier-phases away
  }
  bar_lds();
  // ---- epilogue: all 64 log-softmax values in parallel (8 waves x 8) ----
  {
    int wv = t >> 6;
    for (int st = wv; st < 64; st += 8) {
      float L = Lhist[st * 64 + lane];
      float v = wmax64(L);
      float e2 = EXP2(K1 * (L - v));
      float s3 = wsum64(e2);
      if (lane == 0)
        out[8192 + b * 64 + st] = -LN2 * __builtin_amdgcn_logf(s3);
      if (lane == 1)
        out[b * 64 + st] = outbuf[st];
    }
  }
}

extern "C" void kernel_launch(void* const* d_in, const int* in_sizes, int n_in,
                              void* d_out, int out_size, void* d_ws, size_t ws_size,
                              hipStream_t stream) {
  const float* statics  = (const float*)d_in[0];
  const float* dynamics = (const float*)d_in[1];
  const float* x0       = (const float*)d_in[2];
  const float* sw       = (const float*)d_in[3];
  const float* sb       = (const float*)d_in[4];
  const float* dw       = (const float*)d_in[5];
  const float* db       = (const float*)d_in[6];
  const float* decw     = (const float*)d_in[7];
  const float* decb     = (const float*)d_in[8];
  const float* wih      = (const float*)d_in[9];
  const float* whh      = (const float*)d_in[10];
  const float* bih      = (const float*)d_in[11];
  const float* bhh      = (const float*)d_in[12];
  const float* attn_v   = (const float*)d_in[13];
  const float* attn_W   = (const float*)d_in[14];
  const float* ptr_v    = (const float*)d_in[15];
  const float* ptr_W    = (const float*)d_in[16];
  float* ws  = (float*)d_ws;
  float* out = (float*)d_out;

  hipLaunchKernelGGL(prep_small, dim3(2), dim3(256), 0, stream,
                     wih, decw, decb, bih, ws);
  hipLaunchKernelGGL(prep_big, dim3(1024), dim3(256), 0, stream,
                     statics, dynamics, sw, sb, dw, db, attn_W, ptr_W, ws);
  hipLaunchKernelGGL(drl4tsp_main, dim3(128), dim3(512), 0, stream,
                     statics, x0, whh, attn_W, bhh, attn_v, ptr_v, ws, out);
}